// Round 8
// baseline (681.889 us; speedup 1.0000x reference)
//
#include <hip/hip_runtime.h>
#include <hip/hip_bf16.h>

#define BB 8
#define NN 2048
#define KK 20
#define BN (BB*NN)
#define RSQ 0.99999500003749969f   // 1/sqrt(1+1e-5)

// ---------------- workspace layout (float-slot units), 44.7 MiB baseline ----------------
constexpr size_t OFF_XX  = 0;                          // BN
constexpr size_t OFF_X1  = OFF_XX  + BN;               // BN*64
constexpr size_t OFF_X2  = OFF_X1  + (size_t)BN*64;    // BN*64
constexpr size_t OFF_X3  = OFF_X2  + (size_t)BN*64;    // BN*128
constexpr size_t OFF_X4  = OFF_X3  + (size_t)BN*128;   // BN*256 (split-scratch pre-gather)
constexpr size_t OFF_SC  = OFF_X4  + (size_t)BN*256;   // BN*160 (L1 qp + fallback chunked qp + W5 bf16 tail)
constexpr size_t OFF_ID  = OFF_SC  + (size_t)BN*160;   // int BN*20
constexpr size_t OFF_W5T = OFF_ID  + (size_t)BN*20;    // 512*512
constexpr size_t OFF_MX  = OFF_W5T + 512*512;
constexpr size_t OFF_MN  = OFF_MX  + BB*512;
constexpr size_t OFF_WT2 = OFF_MN  + BB*512;           // cat [64][128]
constexpr size_t OFF_WT3 = OFF_WT2 + 8192;             // cat [64][256]
constexpr size_t OFF_WT4 = OFF_WT3 + 16384;            // cat [128][512]
constexpr size_t WS_END  = OFF_WT4 + 65536;            // 11,714,560 floats
// big region (probed at runtime): 8-batch dist; reused as qp buffer + bf16 xcat post-sel
constexpr size_t OFF_BIG = WS_END;
constexpr size_t OFF_XCAT = OFF_BIG + (size_t)16*1024*1024;  // bf16 xcat h/m/l (dist region tail, post-KNN)
constexpr size_t WS_BIG_END = OFF_BIG + (size_t)BB*NN*NN;   // 172.7 MiB
static_assert(OFF_ID - OFF_X3 >= (size_t)4096*2048, "fallback dual dist fits");
static_assert(OFF_XCAT + (size_t)BN*768 <= WS_BIG_END, "xcat h/m/l fits in dist region");

typedef unsigned short u16;
typedef __attribute__((ext_vector_type(8))) short short8;
typedef __attribute__((ext_vector_type(8))) unsigned short ushort8;
typedef __attribute__((ext_vector_type(4))) float f32x4;

__device__ inline unsigned encf(float f){ unsigned u=__float_as_uint(f); return (u&0x80000000u)? ~u : (u|0x80000000u); }
__device__ inline float decf(unsigned e){ unsigned u=(e&0x80000000u)? (e&0x7fffffffu) : ~e; return __uint_as_float(u); }
__device__ inline float lrelu(float h){ return h>=0.f ? h : 0.2f*h; }
__device__ inline u16 bf16rne(float x){
  unsigned u = __float_as_uint(x);
  return (u16)((u + 0x7FFFu + ((u>>16)&1u)) >> 16);
}
__device__ inline float bf16f(u16 h){ return __uint_as_float((unsigned)h<<16); }
// exact 3-way split: x == h + m + l for normal fp32 (24 mantissa bits covered)
__device__ inline void bf16split3(float v, u16& h, u16& m, u16& l){
  h = bf16rne(v);  float r1 = v  - bf16f(h);
  m = bf16rne(r1); float r2 = r1 - bf16f(m);
  l = bf16rne(r2);
}

__device__ inline float readlane_f(float v, int sl){
  return __int_as_float(__builtin_amdgcn_readlane(__float_as_int(v), sl));
}
// lane i <- lane i-1 within 16-lane DPP rows (lanes 0/16/32/48 keep own value).
// Only lanes 1..19 are consumed; lane 16 patched with readlane(…,15) at use site.
__device__ inline float dpp_up1_f(float v){
  return __int_as_float(__builtin_amdgcn_update_dpp(__float_as_int(v), __float_as_int(v), 0x111, 0xf, 0xf, false));
}
__device__ inline int dpp_up1_i(int v){
  return __builtin_amdgcn_update_dpp(v, v, 0x111, 0xf, 0xf, false);
}

// Wave-cooperative sorted-top-20 insertion (cv known > theta on call).
// Tie-correct rank (equal values: lower index ranks first, matching lax.top_k).
// Cross-lane shift via DPP row_shr:1 (+lane-16 patch) -- no ds_bpermute in the chain.
#define INSERT_CAND(cv, ci) { \
  unsigned long long mge = __ballot((lv > cv) || (lv == cv && li < ci)); \
  int pos = __popcll(mge); \
  float upv = dpp_up1_f(lv); \
  int   upi = dpp_up1_i(li); \
  float p15v = readlane_f(lv, 15); \
  int   p15i = __builtin_amdgcn_readlane(li, 15); \
  upv = (lane == 16) ? p15v : upv; \
  upi = (lane == 16) ? p15i : upi; \
  bool shift = (lane > pos) && (lane < KK); \
  lv = (lane == pos) ? cv : (shift ? upv : lv); \
  li = (lane == pos) ? ci : (shift ? upi : li); \
  theta = readlane_f(lv, KK-1); }

// Bitonic full sort of 64 (value desc, index asc on ties) across lanes; (v,vi) in registers.
#define BITONIC64_DESC(v, vi) { \
  _Pragma("unroll") \
  for(int k=2; k<=64; k<<=1){ \
    _Pragma("unroll") \
    for(int j=k>>1; j>=1; j>>=1){ \
      float ov = __shfl_xor(v, j); \
      int   oi = __shfl_xor(vi, j); \
      int partner = lane ^ j; \
      bool keepFirst = (((lane & k) == 0)) == (lane < partner); \
      bool before = (v > ov) || (v == ov && vi < oi); \
      if(keepFirst != before){ v = ov; vi = oi; } \
    } \
  } }

// ======== fragment-major tiled split layout ========
// split[rowGroup][kTile][lane=64][8]  (u16). lane l -> row = rg*16 + (l&15), k = kt*32 + (l>>4)*8.
// A wave's MFMA fragment load = base + lane*16B : one contiguous 1KB transaction.

// ---------------- prep: cat-transposed weights + W5T + W5 bf16 3-split (tiled) + enc ----------------
__global__ void prep_k(const float* W5, const float* W2, const float* W3, const float* W4,
                       float* W5T, float* WT2, float* WT3, float* WT4,
                       u16* w5h, u16* w5m, u16* w5l,
                       unsigned* mx, unsigned* mn){
  int i = blockIdx.x*256 + threadIdx.x;     // 262144
  { int o = i>>9, c = i&511; W5T[c*512+o] = W5[i]; }
  { // tiled split of W5 (B-side rows = output cols o, k = input c). KT=16.
    int rg = i>>13, kt = (i>>9)&15, l = (i>>3)&63, j = i&7;
    int o = rg*16 + (l&15);
    int c = kt*32 + ((l>>4)<<3) + j;
    u16 h,m,lo; bf16split3(W5[(size_t)o*512 + c], h, m, lo);
    w5h[i]=h; w5m[i]=m; w5l[i]=lo; }
  if(i < 65536){ int c = i>>9, o = i&511;   // W4: [256][256] -> cat [128][512]
    WT4[i] = (o<256) ? W4[(size_t)o*256 + c] : W4[(size_t)(o-256)*256 + 128 + c]; }
  if(i < 16384){ int c = i>>8, o = i&255;   // W3: [128][128] -> cat [64][256]
    WT3[i] = (o<128) ? W3[(size_t)o*128 + c] : W3[(size_t)(o-128)*128 + 64 + c]; }
  if(i <  8192){ int c = i>>7, o = i&127;   // W2: [64][128] -> cat [64][128]
    WT2[i] = (o<64) ? W2[(size_t)o*128 + c] : W2[(size_t)(o-64)*128 + 64 + c]; }
  if(i <  4096){ mx[i] = 0x007FFFFFu; mn[i] = 0xFF800000u; }
}

// ---------------- KNN ----------------
template<int C>
__launch_bounds__(256) __global__ void sqnorm_k(const float* X, float* xx){
  int i = blockIdx.x*256 + threadIdx.x;   // BN
  const float* r = X + (size_t)i*C;
  float s = 0.f;
  #pragma unroll
  for(int c=0;c<C;c++) s = fmaf(r[c], r[c], s);
  xx[i] = s;
}

// 3-way bf16 split of X [BN][C] into fragment-major tiled layout.
template<int C>
__launch_bounds__(256) __global__ void split_k(const float* __restrict__ X,
    u16* __restrict__ xh, u16* __restrict__ xm, u16* __restrict__ xl){
  constexpr int KT = C/32;
  const size_t t = (size_t)blockIdx.x*256 + threadIdx.x;   // BN*C/8 chunks
  const int l = (int)(t & 63);
  const size_t tile = t >> 6;               // rgG*KT + kt
  const int kt = (int)(tile & (KT-1));
  const size_t rgG = tile / KT;             // global row group (BN/16 total)
  const size_t row = rgG*16 + (l & 15);
  const int k = kt*32 + ((l>>4)<<3);
  const float* p = X + row*C + k;
  float4 v0 = *(const float4*)p;
  float4 v1 = *(const float4*)(p+4);
  float vs[8] = {v0.x,v0.y,v0.z,v0.w,v1.x,v1.y,v1.z,v1.w};
  ushort8 H,M,L;
  #pragma unroll
  for(int j=0;j<8;j++){ u16 h,m,lo; bf16split3(vs[j],h,m,lo); H[j]=h; M[j]=m; L[j]=lo; }
  *(ushort8*)(xh + t*8) = H;
  *(ushort8*)(xm + t*8) = M;
  *(ushort8*)(xl + t*8) = L;
}

#define FMA_ROW(I) \
  acc[I][0]=fmaf(a,b0v,acc[I][0]); acc[I][1]=fmaf(a,b1v,acc[I][1]); \
  acc[I][2]=fmaf(a,b2v,acc[I][2]); acc[I][3]=fmaf(a,b3v,acc[I][3]); \
  acc[I][4]=fmaf(a,b4v,acc[I][4]); acc[I][5]=fmaf(a,b5v,acc[I][5]); \
  acc[I][6]=fmaf(a,b6v,acc[I][6]); acc[I][7]=fmaf(a,b7v,acc[I][7]);

// fallback fp32 dist GEMM
template<int C>
__launch_bounds__(256) __global__ void gemm_dist_k(const float* __restrict__ X, const float* __restrict__ xx,
                                                   float* __restrict__ dist, int b0){
  constexpr int AST = 188;
  __shared__ __align__(16) float a_sh[16*AST];
  __shared__ __align__(16) float b_sh[16*AST];
  __shared__ float sxn[128], sxm[128];
  const int tid = threadIdx.x;
  const int b   = b0 + blockIdx.z;
  const int mtile = blockIdx.x*128;
  const int ntile = blockIdx.y*128;
  const int tn = tid & 15, tm = tid >> 4;
  const float* Xb  = X  + (size_t)b*NN*C;
  const float* xxb = xx + (size_t)b*NN;
  if(tid < 128) sxn[tid] = xxb[ntile + tid];
  else          sxm[tid-128] = xxb[mtile + tid-128];
  float acc[8][8];
  #pragma unroll
  for(int i=0;i<8;i++){
    #pragma unroll
    for(int j=0;j<8;j++) acc[i][j]=0.f;
  }
  for(int cc=0; cc<C; cc+=16){
    __syncthreads();
    #pragma unroll
    for(int s=0;s<2;s++){
      int ii = tid + 256*s; int r = ii>>2, q = ii&3;
      int pr = r + 4*(r>>3);
      float4 va = *(const float4*)&Xb[(size_t)(ntile + r)*C + cc + 4*q];
      a_sh[(4*q+0)*AST + pr]=va.x; a_sh[(4*q+1)*AST + pr]=va.y;
      a_sh[(4*q+2)*AST + pr]=va.z; a_sh[(4*q+3)*AST + pr]=va.w;
      float4 vb = *(const float4*)&Xb[(size_t)(mtile + r)*C + cc + 4*q];
      b_sh[(4*q+0)*AST + pr]=vb.x; b_sh[(4*q+1)*AST + pr]=vb.y;
      b_sh[(4*q+2)*AST + pr]=vb.z; b_sh[(4*q+3)*AST + pr]=vb.w;
    }
    __syncthreads();
    #pragma unroll
    for(int c=0;c<16;c++){
      float4 A0 = *(const float4*)&a_sh[c*AST + 12*tn];
      float4 A1 = *(const float4*)&a_sh[c*AST + 12*tn + 4];
      float4 B0 = *(const float4*)&b_sh[c*AST + 12*tm];
      float4 B1 = *(const float4*)&b_sh[c*AST + 12*tm + 4];
      float b0v=B0.x,b1v=B0.y,b2v=B0.z,b3v=B0.w,b4v=B1.x,b5v=B1.y,b6v=B1.z,b7v=B1.w;
      float a;
      a=A0.x; FMA_ROW(0)
      a=A0.y; FMA_ROW(1)
      a=A0.z; FMA_ROW(2)
      a=A0.w; FMA_ROW(3)
      a=A1.x; FMA_ROW(4)
      a=A1.y; FMA_ROW(5)
      a=A1.z; FMA_ROW(6)
      a=A1.w; FMA_ROW(7)
    }
  }
  float xnr[8], xmr[8];
  #pragma unroll
  for(int i=0;i<8;i++){ xnr[i]=sxn[tn*8+i]; xmr[i]=sxm[tm*8+i]; }
  const size_t rowb = (size_t)blockIdx.z*NN + ntile + tn*8;
  #pragma unroll
  for(int i=0;i<8;i++){
    float4 w0, w1;
    w0.x=(2.f*acc[i][0]-xnr[i])-xmr[0]; w0.y=(2.f*acc[i][1]-xnr[i])-xmr[1];
    w0.z=(2.f*acc[i][2]-xnr[i])-xmr[2]; w0.w=(2.f*acc[i][3]-xnr[i])-xmr[3];
    w1.x=(2.f*acc[i][4]-xnr[i])-xmr[4]; w1.y=(2.f*acc[i][5]-xnr[i])-xmr[5];
    w1.z=(2.f*acc[i][6]-xnr[i])-xmr[6]; w1.w=(2.f*acc[i][7]-xnr[i])-xmr[7];
    float* dp = dist + (rowb + i)*NN + mtile + tm*8;
    *(float4*)dp = w0;
    *(float4*)(dp+4) = w1;
  }
}

// big path: exact-fp32-quality dist via split-bf16 MFMA (6 products of 3-way split).
// Tiled fragment-major operands: every load = base + lane*16B (coalesced 1KB wave transaction).
template<int C>
__launch_bounds__(256) __global__ void mfma_dist_k(const u16* __restrict__ xh, const u16* __restrict__ xm,
    const u16* __restrict__ xl, const float* __restrict__ xx, float* __restrict__ dist){
  constexpr int KT = C/32;
  const int tid = threadIdx.x;
  const int l  = tid & 63, wv = tid >> 6;
  const int lg = l >> 4, lr = l & 15;
  const int b  = blockIdx.z;
  const int qrow0 = blockIdx.y*128 + (wv>>1)*64;   // query rows (A side, dist row)
  const int crow0 = blockIdx.x*128 + (wv&1)*64;    // candidate rows (B side, dist col)
  const size_t brg = (size_t)b*(NN/16);
  f32x4 acc[4][4];
  #pragma unroll
  for(int m=0;m<4;m++){
    #pragma unroll
    for(int n=0;n<4;n++) acc[m][n] = (f32x4){0.f,0.f,0.f,0.f};
  }
  const size_t abase = (brg + (qrow0>>4))*KT*512 + (size_t)l*8;
  const size_t bbase = (brg + (crow0>>4))*KT*512 + (size_t)l*8;
  for(int kt=0; kt<KT; kt++){
    short8 Ah[4], Am[4], Al[4], Bh[4], Bm[4], Bl[4];
    #pragma unroll
    for(int m=0;m<4;m++){
      size_t o = abase + (size_t)(m*KT + kt)*512;
      Ah[m] = *(const short8*)(xh + o);
      Am[m] = *(const short8*)(xm + o);
      Al[m] = *(const short8*)(xl + o);
    }
    #pragma unroll
    for(int n=0;n<4;n++){
      size_t o = bbase + (size_t)(n*KT + kt)*512;
      Bh[n] = *(const short8*)(xh + o);
      Bm[n] = *(const short8*)(xm + o);
      Bl[n] = *(const short8*)(xl + o);
    }
    #pragma unroll
    for(int m=0;m<4;m++){
      #pragma unroll
      for(int n=0;n<4;n++){
        acc[m][n] = __builtin_amdgcn_mfma_f32_16x16x32_bf16(Ah[m], Bh[n], acc[m][n], 0, 0, 0);
        acc[m][n] = __builtin_amdgcn_mfma_f32_16x16x32_bf16(Ah[m], Bm[n], acc[m][n], 0, 0, 0);
        acc[m][n] = __builtin_amdgcn_mfma_f32_16x16x32_bf16(Am[m], Bh[n], acc[m][n], 0, 0, 0);
        acc[m][n] = __builtin_amdgcn_mfma_f32_16x16x32_bf16(Ah[m], Bl[n], acc[m][n], 0, 0, 0);
        acc[m][n] = __builtin_amdgcn_mfma_f32_16x16x32_bf16(Al[m], Bh[n], acc[m][n], 0, 0, 0);
        acc[m][n] = __builtin_amdgcn_mfma_f32_16x16x32_bf16(Am[m], Bm[n], acc[m][n], 0, 0, 0);
      }
    }
  }
  const float* xxb = xx + (size_t)b*NN;
  float xxc[4];
  #pragma unroll
  for(int n=0;n<4;n++) xxc[n] = xxb[crow0 + n*16 + lr];
  #pragma unroll
  for(int m=0;m<4;m++){
    #pragma unroll
    for(int r=0;r<4;r++){
      int qr = qrow0 + m*16 + 4*lg + r;
      float xq = xxb[qr];
      float* dp = dist + ((size_t)b*NN + qr)*NN + crow0;
      #pragma unroll
      for(int n=0;n<4;n++) dp[n*16 + lr] = (2.f*acc[m][n][r] - xq) - xxc[n];
    }
  }
}

// Wave-cooperative top-20: bitonic-64 warm start + slim insertions, float4 scan.
__launch_bounds__(256) __global__ void sel_k(const float* __restrict__ dist, int* __restrict__ id,
                                             int b0, int nrows){
  const int w = (blockIdx.x*256 + threadIdx.x) >> 6;
  const int lane = threadIdx.x & 63;
  if(w >= nrows) return;
  const float* dr = dist + (size_t)w*NN;
  // group 0: load 256 candidates; bitonic-sort the j=0 subset; insert j=1..3
  float4 c0 = *(const float4*)&dr[4*lane];
  float v = c0.x; int vi = 4*lane;
  BITONIC64_DESC(v, vi)
  float lv = (lane < KK) ? v : -INFINITY;
  int   li = (lane < KK) ? vi : 0;
  float theta = readlane_f(lv, KK-1);
  #pragma unroll
  for(int j=1;j<4;j++){
    float cand = (j==1)?c0.y:(j==2)?c0.z:c0.w;
    unsigned long long bal = __ballot(cand > theta);
    while(bal){
      int bpos = __ffsll((unsigned long long)bal) - 1;
      bal &= bal - 1;
      float cv = readlane_f(cand, bpos);
      if(cv > theta){
        int ci = 4*bpos + j;
        INSERT_CAND(cv, ci)
      }
    }
  }
  for(int ms=256; ms<NN; ms+=256){
    float4 c4 = *(const float4*)&dr[ms + 4*lane];
    #pragma unroll
    for(int j=0;j<4;j++){
      float cand = (j==0)?c4.x:(j==1)?c4.y:(j==2)?c4.z:c4.w;
      unsigned long long bal = __ballot(cand > theta);
      while(bal){
        int bpos = __ffsll((unsigned long long)bal) - 1;
        bal &= bal - 1;
        float cv = readlane_f(cand, bpos);
        if(cv > theta){
          int ci = ms + 4*bpos + j;
          INSERT_CAND(cv, ci)
        }
      }
    }
  }
  if(lane < KK) id[((size_t)b0*NN + w)*KK + lane] = li;
}

// L1 fused: inline C=3 distances with precomputed candidate norms (xx), bitonic warm start.
__launch_bounds__(256) __global__ void sel3_k(const float* __restrict__ X, const float* __restrict__ xx,
                                              int* __restrict__ id){
  const int gw = (blockIdx.x*256 + threadIdx.x) >> 6;
  const int lane = threadIdx.x & 63;
  const int b = gw >> 11, n = gw & 2047;
  const float* Xb  = X + (size_t)b*NN*3;
  const float* xxb = xx + (size_t)b*NN;
  const float x0v = Xb[n*3], x1v = Xb[n*3+1], x2v = Xb[n*3+2];
  const float xxn = xxb[n];
  float lv, theta; int li;
  {
    const float* p = Xb + (size_t)(4*lane)*3;
    float4 va = *(const float4*)p;
    float4 vb = *(const float4*)(p+4);
    float4 vc = *(const float4*)(p+8);
    float4 xm4 = *(const float4*)&xxb[4*lane];
    float cx[4] = {va.x, va.w, vb.z, vc.y};
    float cy[4] = {va.y, vb.x, vb.w, vc.z};
    float cz[4] = {va.z, vb.y, vc.x, vc.w};
    float xm[4] = {xm4.x, xm4.y, xm4.z, xm4.w};
    float cd[4];
    #pragma unroll
    for(int j=0;j<4;j++){
      float s = 0.f;
      s = fmaf(x0v, cx[j], s); s = fmaf(x1v, cy[j], s); s = fmaf(x2v, cz[j], s);
      cd[j] = (2.f*s - xxn) - xm[j];
    }
    float v = cd[0]; int vi = 4*lane;
    BITONIC64_DESC(v, vi)
    lv = (lane < KK) ? v : -INFINITY;
    li = (lane < KK) ? vi : 0;
    theta = readlane_f(lv, KK-1);
    #pragma unroll
    for(int j=1;j<4;j++){
      float cand = cd[j];
      unsigned long long bal = __ballot(cand > theta);
      while(bal){
        int bpos = __ffsll((unsigned long long)bal) - 1;
        bal &= bal - 1;
        float cv = readlane_f(cand, bpos);
        if(cv > theta){
          int ci = 4*bpos + j;
          INSERT_CAND(cv, ci)
        }
      }
    }
  }
  for(int ms=256; ms<NN; ms+=256){
    const float* p = Xb + (size_t)(ms + 4*lane)*3;
    float4 va = *(const float4*)p;
    float4 vb = *(const float4*)(p+4);
    float4 vc = *(const float4*)(p+8);
    float4 xm4 = *(const float4*)&xxb[ms + 4*lane];
    float cx[4] = {va.x, va.w, vb.z, vc.y};
    float cy[4] = {va.y, vb.x, vb.w, vc.z};
    float cz[4] = {va.z, vb.y, vc.x, vc.w};
    float xm[4] = {xm4.x, xm4.y, xm4.z, xm4.w};
    float cd[4];
    #pragma unroll
    for(int j=0;j<4;j++){
      float s = 0.f;
      s = fmaf(x0v, cx[j], s); s = fmaf(x1v, cy[j], s); s = fmaf(x2v, cz[j], s);
      cd[j] = (2.f*s - xxn) - xm[j];
    }
    #pragma unroll
    for(int j=0;j<4;j++){
      float cand = cd[j];
      unsigned long long bal = __ballot(cand > theta);
      while(bal){
        int bpos = __ffsll((unsigned long long)bal) - 1;
        bal &= bal - 1;
        float cv = readlane_f(cand, bpos);
        if(cv > theta){
          int ci = ms + 4*bpos + j;
          INSERT_CAND(cv, ci)
        }
      }
    }
  }
  if(lane < KK) id[(size_t)gw*KK + lane] = li;
}

// ---------------- qp ----------------
// L1: writes interleaved qp[row][128]: q at 0..63, p at 64..127
__launch_bounds__(256) __global__ void qp3_k(const float* X, const float* W, float* qp){
  const int t   = blockIdx.x*256 + threadIdx.x;
  const int row = t >> 3;
  const int c0  = (t & 7) * 8;
  float xn[3];
  #pragma unroll
  for(int c=0;c<3;c++) xn[c] = X[(size_t)row*3 + c];
  for(int oi=c0; oi<c0+8; oi++){
    const float* w = W + (size_t)oi*6;
    float aq=0.f, ap=0.f;
    #pragma unroll
    for(int c=0;c<3;c++){ aq = fmaf(xn[c], w[c], aq); ap = fmaf(xn[c], w[3+c], ap); }
    qp[(size_t)row*128 + oi]      = aq;
    qp[(size_t)row*128 + 64 + oi] = ap;
  }
}

// Tiled qp GEMM (big path): C[BN x W2C] = X[BN x CIN] * WTcat[CIN x W2C].
template<int CIN, int W2C>
__launch_bounds__(256) __global__ void qp_gemm_k(const float* __restrict__ X, const float* __restrict__ WT,
                                                 float* __restrict__ qp){
  constexpr int ASTA = 92;    // 64 rows, pad 4 per 8: max pr = 63+28 = 91
  constexpr int ASTB = 188;
  __shared__ __align__(16) float a_sh[16*ASTA];
  __shared__ __align__(16) float b_sh[16*ASTB];
  const int tid = threadIdx.x;
  const int otile = blockIdx.x*128;
  const int rtile = blockIdx.y*64;
  const int tn = tid & 15, tm = tid >> 4;
  const int aoff = 4*tn + 4*(tn>>1);   // padded offset of row 4*tn
  float acc[4][8];
  #pragma unroll
  for(int i=0;i<4;i++){
    #pragma unroll
    for(int j=0;j<8;j++) acc[i][j]=0.f;
  }
  for(int cc=0; cc<CIN; cc+=16){
    __syncthreads();
    { int r = tid>>2, q = tid&3;          // 64 rows x 16 c = 256 float4, 1/thread
      int pr = r + 4*(r>>3);
      float4 va = *(const float4*)&X[(size_t)(rtile + r)*CIN + cc + 4*q];
      a_sh[(4*q+0)*ASTA + pr]=va.x; a_sh[(4*q+1)*ASTA + pr]=va.y;
      a_sh[(4*q+2)*ASTA + pr]=va.z; a_sh[(4*q+3)*ASTA + pr]=va.w; }
    #pragma unroll
    for(int s=0;s<2;s++){                 // 16 c x 128 cols = 512 float4, 2/thread
      int ii = tid + 256*s;
      int cl = ii>>5, o4 = ii&31;
      float4 vb = *(const float4*)&WT[(size_t)(cc+cl)*W2C + otile + 4*o4];
      *(float4*)&b_sh[cl*ASTB + 4*o4 + 4*(o4>>1)] = vb;
    }
    __syncthreads();
    #pragma unroll
    for(int c=0;c<16;c++){
      float4 A0 = *(const float4*)&a_sh[c*ASTA + aoff];
      float4 B0 = *(const float4*)&b_sh[c*ASTB + 12*tm];
      float4 B1 = *(const float4*)&b_sh[c*ASTB + 12*tm + 4];
      float b0v=B0.x,b1v=B0.y,b2v=B0.z,b3v=B0.w,b4v=B1.x,b5v=B1.y,b6v=B1.z,b7v=B1.w;
      float a;
      a=A0.x; FMA_ROW(0)
      a=A0.y; FMA_ROW(1)
      a=A0.z; FMA_ROW(2)
      a=A0.w; FMA_ROW(3)
    }
  }
  #pragma unroll
  for(int i=0;i<4;i++){
    float* dp = qp + (size_t)(rtile + tn*4 + i)*W2C + otile + tm*8;
    *(float4*)dp     = make_float4(acc[i][0],acc[i][1],acc[i][2],acc[i][3]);
    *(float4*)(dp+4) = make_float4(acc[i][4],acc[i][5],acc[i][6],acc[i][7]);
  }
}

// Gather from interleaved qp[row][2*COUT] (q | p); base = p - q computed here (bit-exact).
template<int COUT>
__launch_bounds__(256) __global__ void gather_qp_k(const float* __restrict__ qp, const int* __restrict__ idx,
    const float* g, const float* bb, float* out){
  const int t  = blockIdx.x*256 + threadIdx.x;   // BN*COUT
  const int o  = t % COUT;
  const int bn = t / COUT;
  const int b  = bn >> 11;
  const int* id = idx + (size_t)bn*KK;
  float qv = qp[(size_t)bn*(2*COUT) + o];
  float pv = qp[(size_t)bn*(2*COUT) + COUT + o];
  float base = pv - qv;
  float mx = -INFINITY, mn = INFINITY;
  #pragma unroll
  for(int k=0;k<KK;k++){
    int ik = id[k];
    float v = qp[((size_t)((b<<11) + ik))*(2*COUT) + o];
    mx = fmaxf(mx, v); mn = fminf(mn, v);
  }
  float a  = g[o] * RSQ;
  float bo = bb[o];
  out[(size_t)bn*COUT + o] = lrelu((a >= 0.f ? a*(mx+base) : a*(mn+base)) + bo);
}

// ---- fallback chunked qp (cat weight layout) + chunked gather ----
template<int CIN, int COUT>
__launch_bounds__(256) __global__ void qp64T_k(const float* __restrict__ X, const float* __restrict__ WT,
                                               int cb, float* __restrict__ q, float* __restrict__ bs){
  const int t   = blockIdx.x*256 + threadIdx.x;
  const int row = t >> 3;
  const int o0  = cb + (t & 7) * 8;
  float xn[CIN];
  #pragma unroll
  for(int c=0;c<CIN;c+=4){ float4 v = *(const float4*)(X + (size_t)row*CIN + c);
    xn[c]=v.x; xn[c+1]=v.y; xn[c+2]=v.z; xn[c+3]=v.w; }
  float aq[8], ap[8];
  #pragma unroll
  for(int j=0;j<8;j++){ aq[j]=0.f; ap[j]=0.f; }
  #pragma unroll 4
  for(int c=0;c<CIN;c++){
    float xc = xn[c];
    float4 wa0 = *(const float4*)&WT[(size_t)c*(2*COUT) + o0];
    float4 wa1 = *(const float4*)&WT[(size_t)c*(2*COUT) + o0 + 4];
    float4 wb0 = *(const float4*)&WT[(size_t)c*(2*COUT) + COUT + o0];
    float4 wb1 = *(const float4*)&WT[(size_t)c*(2*COUT) + COUT + o0 + 4];
    aq[0]=fmaf(xc,wa0.x,aq[0]); aq[1]=fmaf(xc,wa0.y,aq[1]); aq[2]=fmaf(xc,wa0.z,aq[2]); aq[3]=fmaf(xc,wa0.w,aq[3]);
    aq[4]=fmaf(xc,wa1.x,aq[4]); aq[5]=fmaf(xc,wa1.y,aq[5]); aq[6]=fmaf(xc,wa1.z,aq[6]); aq[7]=fmaf(xc,wa1.w,aq[7]);
    ap[0]=fmaf(xc,wb0.x,ap[0]); ap[1]=fmaf(xc,wb0.y,ap[1]); ap[2]=fmaf(xc,wb0.z,ap[2]); ap[3]=fmaf(xc,wb0.w,ap[3]);
    ap[4]=fmaf(xc,wb1.x,ap[4]); ap[5]=fmaf(xc,wb1.y,ap[5]); ap[6]=fmaf(xc,wb1.z,ap[6]); ap[7]=fmaf(xc,wb1.w,ap[7]);
  }
  float* qpp = q  + (size_t)row*64 + (o0-cb);
  float* bpp = bs + (size_t)row*64 + (o0-cb);
  *(float4*)qpp     = make_float4(aq[0],aq[1],aq[2],aq[3]);
  *(float4*)(qpp+4) = make_float4(aq[4],aq[5],aq[6],aq[7]);
  *(float4*)bpp     = make_float4(ap[0]-aq[0],ap[1]-aq[1],ap[2]-aq[2],ap[3]-aq[3]);
  *(float4*)(bpp+4) = make_float4(ap[4]-aq[4],ap[5]-aq[5],ap[6]-aq[6],ap[7]-aq[7]);
}

template<int CFULL>
__launch_bounds__(256) __global__ void gather_chunk_k(const float* q, const float* bs, const int* idx,
    const float* g, const float* bb, int cb, float* out){
  const int t  = blockIdx.x*256 + threadIdx.x;
  const int o  = t & 63;
  const int bn = t >> 6;
  const int b  = bn >> 11;
  const int* id = idx + (size_t)bn*KK;
  float base = bs[t];
  float mx = -INFINITY, mn = INFINITY;
  #pragma unroll
  for(int k=0;k<KK;k++){
    int ik = id[k];
    float v = q[((size_t)((b<<11) + ik))*64 + o];
    mx = fmaxf(mx, v); mn = fminf(mn, v);
  }
  float a  = g[cb+o] * RSQ;
  float bo = bb[cb+o];
  out[(size_t)bn*CFULL + cb + o] = lrelu((a >= 0.f ? a*(mx+base) : a*(mn+base)) + bo);
}

// ---------------- head (fallback): fp32 GEMM-tiled cat x W5T with fused max/min ----------------
__launch_bounds__(256) __global__ void w5gemm_k(const float* __restrict__ x1, const float* __restrict__ x2,
    const float* __restrict__ x3, const float* __restrict__ x4,
    const float* __restrict__ W5T, unsigned* mxe, unsigned* mne){
  constexpr int ASTA = 92;
  constexpr int ASTB = 188;
  __shared__ __align__(16) float a_sh[16*ASTA];
  __shared__ __align__(16) float b_sh[16*ASTB];
  const int tid = threadIdx.x;
  const int otile = blockIdx.x*128;
  const int rtile = blockIdx.y*64;
  const int b     = blockIdx.z;
  const int tn = tid & 15, tm = tid >> 4;
  const int aoff = 4*tn + 4*(tn>>1);
  const size_t row0 = (size_t)b*NN + rtile;
  float acc[4][8];
  #pragma unroll
  for(int i=0;i<4;i++){
    #pragma unroll
    for(int j=0;j<8;j++) acc[i][j]=0.f;
  }
  for(int cc=0; cc<512; cc+=16){
    const float* src; int stride, coff;
    if(cc<64)      { src=x1; stride=64;  coff=cc; }
    else if(cc<128){ src=x2; stride=64;  coff=cc-64; }
    else if(cc<256){ src=x3; stride=128; coff=cc-128; }
    else           { src=x4; stride=256; coff=cc-256; }
    __syncthreads();
    { int r = tid>>2, q = tid&3;
      int pr = r + 4*(r>>3);
      float4 va = *(const float4*)&src[(row0 + r)*stride + coff + 4*q];
      a_sh[(4*q+0)*ASTA + pr]=va.x; a_sh[(4*q+1)*ASTA + pr]=va.y;
      a_sh[(4*q+2)*ASTA + pr]=va.z; a_sh[(4*q+3)*ASTA + pr]=va.w; }
    #pragma unroll
    for(int s=0;s<2;s++){
      int ii = tid + 256*s;
      int cl = ii>>5, o4 = ii&31;
      float4 vb = *(const float4*)&W5T[(size_t)(cc+cl)*512 + otile + 4*o4];
      *(float4*)&b_sh[cl*ASTB + 4*o4 + 4*(o4>>1)] = vb;
    }
    __syncthreads();
    #pragma unroll
    for(int c=0;c<16;c++){
      float4 A0 = *(const float4*)&a_sh[c*ASTA + aoff];
      float4 B0 = *(const float4*)&b_sh[c*ASTB + 12*tm];
      float4 B1 = *(const float4*)&b_sh[c*ASTB + 12*tm + 4];
      float b0v=B0.x,b1v=B0.y,b2v=B0.z,b3v=B0.w,b4v=B1.x,b5v=B1.y,b6v=B1.z,b7v=B1.w;
      float a;
      a=A0.x; FMA_ROW(0)
      a=A0.y; FMA_ROW(1)
      a=A0.z; FMA_ROW(2)
      a=A0.w; FMA_ROW(3)
    }
  }
  #pragma unroll
  for(int j=0;j<8;j++){
    float M=-INFINITY, m=INFINITY;
    #pragma unroll
    for(int i=0;i<4;i++){ M=fmaxf(M,acc[i][j]); m=fminf(m,acc[i][j]); }
    #pragma unroll
    for(int d=1; d<16; d<<=1){
      M = fmaxf(M, __shfl_xor(M, d));
      m = fminf(m, __shfl_xor(m, d));
    }
    if(tn == 0){
      int o = otile + tm*8 + j;
      atomicMax(&mxe[b*512+o], encf(M));
      atomicMin(&mne[b*512+o], encf(m));
    }
  }
}

// ---------------- head (big): split-bf16 MFMA ----------------
// xcat 3-split into fragment-major tiled layout (KT=16, row space = BN).
__launch_bounds__(256) __global__ void cvt_k(const float* __restrict__ x1, const float* __restrict__ x2,
    const float* __restrict__ x3, const float* __restrict__ x4,
    u16* __restrict__ xh, u16* __restrict__ xm, u16* __restrict__ xl){
  const size_t t = (size_t)blockIdx.x*256 + threadIdx.x;   // BN*512/8 chunks
  const int l = (int)(t & 63);
  const size_t tile = t >> 6;           // rgG*16 + kt
  const int kt = (int)(tile & 15);
  const size_t rgG = tile >> 4;
  const size_t row = rgG*16 + (l & 15);
  const int col = kt*32 + ((l>>4)<<3);
  const float* src; int stride, coff;
  if(col<64)      { src=x1; stride=64;  coff=col; }
  else if(col<128){ src=x2; stride=64;  coff=col-64; }
  else if(col<256){ src=x3; stride=128; coff=col-128; }
  else            { src=x4; stride=256; coff=col-256; }
  const float* p = src + row*stride + coff;
  float4 v0 = *(const float4*)p;
  float4 v1 = *(const float4*)(p+4);
  float vs[8] = {v0.x,v0.y,v0.z,v0.w,v1.x,v1.y,v1.z,v1.w};
  ushort8 H, M, L;
  #pragma unroll
  for(int j=0;j<8;j++){ u16 h,m,lo; bf16split3(vs[j],h,m,lo); H[j]=h; M[j]=m; L[j]=lo; }
  *(ushort8*)(xh + t*8) = H;
  *(ushort8*)(xm + t*8) = M;
  *(ushort8*)(xl + t*8) = L;
}

// C[16384x512] = xcat * W5^T via 6 bf16 MFMA products (fp32-exact to ~2^-27), fp32 accum.
__launch_bounds__(256) __global__ void w5mfma_k(const u16* __restrict__ xh, const u16* __restrict__ xm,
    const u16* __restrict__ xl,
    const u16* __restrict__ wh, const u16* __restrict__ wm, const u16* __restrict__ wl,
    unsigned* mxe, unsigned* mne){
  const int tid = threadIdx.x;
  const int l  = tid & 63, wv = tid >> 6;
  const int lg = l >> 4, lr = l & 15;
  const int row0 = blockIdx.y*128 + (wv>>1)*64;   // M base of this wave (global BN rows)
  const int col0 = blockIdx.x*128 + (wv&1)*64;    // N base of this wave
  const int b = blockIdx.y >> 4;                  // 16 M-blocks per batch
  f32x4 acc[4][4];
  #pragma unroll
  for(int m=0;m<4;m++){
    #pragma unroll
    for(int n=0;n<4;n++) acc[m][n] = (f32x4){0.f,0.f,0.f,0.f};
  }
  const size_t abase = (size_t)(row0>>4)*16*512 + (size_t)l*8;
  const size_t bbase = (size_t)(col0>>4)*16*512 + (size_t)l*8;
  for(int kt=0; kt<16; kt++){
    short8 Ah[4], Am[4], Al[4], Bh[4], Bm[4], Bl[4];
    #pragma unroll
    for(int m=0;m<4;m++){
      size_t o = abase + (size_t)(m*16 + kt)*512;
      Ah[m] = *(const short8*)(xh + o);
      Am[m] = *(const short8*)(xm + o);
      Al[m] = *(const short8*)(xl + o);
    }
    #pragma unroll
    for(int n=0;n<4;n++){
      size_t o = bbase + (size_t)(n*16 + kt)*512;
      Bh[n] = *(const short8*)(wh + o);
      Bm[n] = *(const short8*)(wm + o);
      Bl[n] = *(const short8*)(wl + o);
    }
    #pragma unroll
    for(int m=0;m<4;m++){
      #pragma unroll
      for(int n=0;n<4;n++){
        acc[m][n] = __builtin_amdgcn_mfma_f32_16x16x32_bf16(Ah[m], Bh[n], acc[m][n], 0, 0, 0);
        acc[m][n] = __builtin_amdgcn_mfma_f32_16x16x32_bf16(Ah[m], Bm[n], acc[m][n], 0, 0, 0);
        acc[m][n] = __builtin_amdgcn_mfma_f32_16x16x32_bf16(Am[m], Bh[n], acc[m][n], 0, 0, 0);
        acc[m][n] = __builtin_amdgcn_mfma_f32_16x16x32_bf16(Ah[m], Bl[n], acc[m][n], 0, 0, 0);
        acc[m][n] = __builtin_amdgcn_mfma_f32_16x16x32_bf16(Al[m], Bh[n], acc[m][n], 0, 0, 0);
        acc[m][n] = __builtin_amdgcn_mfma_f32_16x16x32_bf16(Am[m], Bm[n], acc[m][n], 0, 0, 0);
      }
    }
  }
  #pragma unroll
  for(int n=0;n<4;n++){
    float M = -INFINITY, mnv = INFINITY;
    #pragma unroll
    for(int m=0;m<4;m++){
      #pragma unroll
      for(int r=0;r<4;r++){ float v = acc[m][n][r]; M = fmaxf(M, v); mnv = fminf(mnv, v); }
    }
    M   = fmaxf(M,   __shfl_xor(M, 16));   M   = fmaxf(M,   __shfl_xor(M, 32));
    mnv = fminf(mnv, __shfl_xor(mnv, 16)); mnv = fminf(mnv, __shfl_xor(mnv, 32));
    if(lg == 0){
      int o = col0 + n*16 + lr;
      atomicMax(&mxe[b*512+o], encf(M));
      atomicMin(&mne[b*512+o], encf(mnv));
    }
  }
}

__launch_bounds__(256) __global__ void final_k(const unsigned* mxe, const unsigned* mne,
    const float* g5, const float* b5, const float* Wemb, float* out){
  const int b = blockIdx.x, t = threadIdx.x;
  __shared__ float h[512];
  for(int o=t; o<512; o+=256){
    float mx = decf(mxe[b*512+o]);
    float mn = decf(mne[b*512+o]);
    float a  = g5[o] * RSQ;
    float bo = b5[o];
    float hv = lrelu((a >= 0.f ? a*mx : a*mn) + bo);
    h[o] = hv;
    out[b*512+o] = hv;
  }
  __syncthreads();
  const float* wr = Wemb + (size_t)t*512;
  float s = 0.f;
  for(int o=0;o<512;o+=4){
    float4 w4 = *(const float4*)(wr+o);
    s = fmaf(h[o],w4.x, fmaf(h[o+1],w4.y, fmaf(h[o+2],w4.z, fmaf(h[o+3],w4.w, s))));
  }
  out[4096 + b*256 + t] = s;
}

// ---------------- launch ----------------
extern "C" void kernel_launch(void* const* d_in, const int* in_sizes, int n_in,
                              void* d_out, int out_size, void* d_ws, size_t ws_size,
                              hipStream_t stream) {
  if (ws_size < WS_END * sizeof(float)) return;
  const bool big = ws_size >= WS_BIG_END * sizeof(float);   // deterministic per call

  const float* x0   = (const float*)d_in[0];
  const float* W1   = (const float*)d_in[1];
  const float* g1   = (const float*)d_in[2];
  const float* b1   = (const float*)d_in[3];
  const float* W2   = (const float*)d_in[4];
  const float* g2   = (const float*)d_in[5];
  const float* b2   = (const float*)d_in[6];
  const float* W3   = (const float*)d_in[7];
  const float* g3   = (const float*)d_in[8];
  const float* b3   = (const float*)d_in[9];
  const float* W4   = (const float*)d_in[10];
  const float* g4   = (const float*)d_in[11];
  const float* b4   = (const float*)d_in[12];
  const float* W5   = (const float*)d_in[13];
  const float* g5   = (const float*)d_in[14];
  const float* b5   = (const float*)d_in[15];
  const float* Wemb = (const float*)d_in[16];

  float* ws = (float*)d_ws;
  float* xx = ws + OFF_XX;
  float* x1 = ws + OFF_X1;  float* x2 = ws + OFF_X2;
  float* x3 = ws + OFF_X3;  float* x4 = ws + OFF_X4;
  float* qpS = ws + OFF_SC;               // L1 qp (width 128) + fallback chunked q/bs
  float* bsS = ws + OFF_SC + (size_t)BN*64;
  int*   id = (int*)(ws + OFF_ID);
  float* W5Tf = ws + OFF_W5T;
  unsigned* mxe = (unsigned*)(ws + OFF_MX);
  unsigned* mne = (unsigned*)(ws + OFF_MN);
  float* WT2 = ws + OFF_WT2;
  float* WT3 = ws + OFF_WT3;
  float* WT4 = ws + OFF_WT4;
  float* distD = ws + OFF_X3;   // fallback dual-batch
  float* distS = ws + OFF_X4;   // fallback single-batch
  float* distB = ws + OFF_BIG;  // big: 8-batch dist, then reused as qp buffer / bf16 xcat
  u16* w5h = (u16*)(ws + OFF_SC + (size_t)BN*128);   // SC tail (free in both paths): 3x256KB
  u16* w5m = w5h + 512*512;
  u16* w5l = w5m + 512*512;
  float* out = (float*)d_out;

  prep_k<<<1024,256,0,stream>>>(W5, W2, W3, W4, W5Tf, WT2, WT3, WT4, w5h, w5m, w5l, mxe, mne);

  // layer 1 (3 -> 64): precompute candidate norms, then fused select
  sqnorm_k<3><<<BN/256,256,0,stream>>>(x0, xx);
  sel3_k<<<BN*64/256,256,0,stream>>>(x0, xx, id);
  qp3_k<<<BN*8/256,256,0,stream>>>(x0, W1, qpS);
  gather_qp_k<64><<<BN*64/256,256,0,stream>>>(qpS, id, g1, b1, x1);

  if(big){
    float* qpB = distB;                      // reuse dist region post-sel
    // split scratch lives in x4 region (dead until layer-4 gather)
    u16* sh = (u16*)x4;
    // layer 2 (CIN=64 -> COUT=64, qp width 128)
    { u16* sm = sh + (size_t)BN*64; u16* sl = sm + (size_t)BN*64;
      sqnorm_k<64><<<BN/256,256,0,stream>>>(x1, xx);
      split_k<64><<<BN*64/8/256,256,0,stream>>>(x1, sh, sm, sl);
      mfma_dist_k<64><<<dim3(16,16,8),256,0,stream>>>(sh, sm, sl, xx, distB);
      sel_k<<<(8*NN)/4,256,0,stream>>>(distB, id, 0, 8*NN);
      qp_gemm_k<64,128><<<dim3(1,BN/64),256,0,stream>>>(x1, WT2, qpB);
      gather_qp_k<64><<<BN*64/256,256,0,stream>>>(qpB, id, g2, b2, x2); }
    // layer 3 (64 -> 128, qp width 256)
    { u16* sm = sh + (size_t)BN*64; u16* sl = sm + (size_t)BN*64;
      sqnorm_k<64><<<BN/256,256,0,stream>>>(x2, xx);
      split_k<64><<<BN*64/8/256,256,0,stream>>>(x2, sh, sm, sl);
      mfma_dist_k<64><<<dim3(16,16,8),256,0,stream>>>(sh, sm, sl, xx, distB);
      sel_k<<<(8*NN)/4,256,0,stream>>>(distB, id, 0, 8*NN);
      qp_gemm_k<64,256><<<dim3(2,BN/64),256,0,stream>>>(x2, WT3, qpB);
      gather_qp_k<128><<<BN*128/256,256,0,stream>>>(qpB, id, g3, b3, x3); }
    // layer 4 (128 -> 256, qp width 512)
    { u16* sm = sh + (size_t)BN*128; u16* sl = sm + (size_t)BN*128;
      sqnorm_k<128><<<BN/256,256,0,stream>>>(x3, xx);
      split_k<128><<<BN*128/8/256,256,0,stream>>>(x3, sh, sm, sl);
      mfma_dist_k<128><<<dim3(16,16,8),256,0,stream>>>(sh, sm, sl, xx, distB);
      sel_k<<<(8*NN)/4,256,0,stream>>>(distB, id, 0, 8*NN);
      qp_gemm_k<128,512><<<dim3(4,BN/64),256,0,stream>>>(x3, WT4, qpB);
      gather_qp_k<256><<<BN*256/256,256,0,stream>>>(qpB, id, g4, b4, x4); }
    // head: bf16 3-split (tiled) + 6-product MFMA
    u16* xh = (u16*)(ws + OFF_XCAT);
    u16* xm = xh + (size_t)BN*512;
    u16* xl = xm + (size_t)BN*512;
    cvt_k<<<BN*512/8/256,256,0,stream>>>(x1, x2, x3, x4, xh, xm, xl);
    w5mfma_k<<<dim3(4,128),256,0,stream>>>(xh, xm, xl, w5h, w5m, w5l, mxe, mne);
  } else {
    // fallback: chunked (R12 structure, cat weight layout)
    sqnorm_k<64><<<BN/256,256,0,stream>>>(x1, xx);
    for(int r=0;r<4;r++){
      gemm_dist_k<64><<<dim3(16,16,2),256,0,stream>>>(x1, xx, distD, 2*r);
      sel_k<<<(2*NN)/4,256,0,stream>>>(distD, id, 2*r, 2*NN);
    }
    qp64T_k<64,64><<<BN*8/256,256,0,stream>>>(x1, WT2, 0, qpS, bsS);
    gather_chunk_k<64><<<BN*64/256,256,0,stream>>>(qpS, bsS, id, g2, b2, 0, x2);

    sqnorm_k<64><<<BN/256,256,0,stream>>>(x2, xx);
    for(int r=0;r<4;r++){
      gemm_dist_k<64><<<dim3(16,16,2),256,0,stream>>>(x2, xx, distD, 2*r);
      sel_k<<<(2*NN)/4,256,0,stream>>>(distD, id, 2*r, 2*NN);
    }
    for(int cb=0; cb<128; cb+=64){
      qp64T_k<64,128><<<BN*8/256,256,0,stream>>>(x2, WT3, cb, qpS, bsS);
      gather_chunk_k<128><<<BN*64/256,256,0,stream>>>(qpS, bsS, id, g3, b3, cb, x3);
    }

    sqnorm_k<128><<<BN/256,256,0,stream>>>(x3, xx);
    for(int r=0;r<8;r++){
      gemm_dist_k<128><<<dim3(16,16,1),256,0,stream>>>(x3, xx, distS, r);
      sel_k<<<NN/4,256,0,stream>>>(distS, id, r, NN);
    }
    for(int cb=0; cb<256; cb+=64){
      qp64T_k<128,256><<<BN*8/256,256,0,stream>>>(x3, WT4, cb, qpS, bsS);
      gather_chunk_k<256><<<BN*64/256,256,0,stream>>>(qpS, bsS, id, g4, b4, cb, x4);
    }
    w5gemm_k<<<dim3(4,32,8),256,0,stream>>>(x1, x2, x3, x4, W5Tf, mxe, mne);
  }

  final_k<<<BB,256,0,stream>>>(mxe, mne, g5, b5, Wemb, out);
}

// Round 9
// 617.941 us; speedup vs baseline: 1.1035x; 1.1035x over previous
//
#include <hip/hip_runtime.h>
#include <hip/hip_bf16.h>

#define BB 8
#define NN 2048
#define KK 20
#define BN (BB*NN)
#define RSQ 0.99999500003749969f   // 1/sqrt(1+1e-5)

// ---------------- workspace layout (float-slot units), 44.7 MiB baseline ----------------
constexpr size_t OFF_XX  = 0;                          // BN
constexpr size_t OFF_X1  = OFF_XX  + BN;               // BN*64
constexpr size_t OFF_X2  = OFF_X1  + (size_t)BN*64;    // BN*64
constexpr size_t OFF_X3  = OFF_X2  + (size_t)BN*64;    // BN*128
constexpr size_t OFF_X4  = OFF_X3  + (size_t)BN*128;   // BN*256 (split-scratch pre-gather)
constexpr size_t OFF_SC  = OFF_X4  + (size_t)BN*256;   // BN*160 (L1 qp + fallback chunked qp + W5 bf16 tail)
constexpr size_t OFF_ID  = OFF_SC  + (size_t)BN*160;   // int BN*20
constexpr size_t OFF_W5T = OFF_ID  + (size_t)BN*20;    // 512*512
constexpr size_t OFF_MX  = OFF_W5T + 512*512;
constexpr size_t OFF_MN  = OFF_MX  + BB*512;
constexpr size_t OFF_WT2 = OFF_MN  + BB*512;           // cat [64][128]
constexpr size_t OFF_WT3 = OFF_WT2 + 8192;             // cat [64][256]
constexpr size_t OFF_WT4 = OFF_WT3 + 16384;            // cat [128][512]
constexpr size_t WS_END  = OFF_WT4 + 65536;            // 11,714,560 floats
// big region (probed at runtime): 8-batch dist; reused as qp buffer + bf16 xcat post-sel
constexpr size_t OFF_BIG = WS_END;
constexpr size_t OFF_XCAT = OFF_BIG + (size_t)16*1024*1024;  // bf16 xcat h/m/l (dist region tail, post-KNN)
constexpr size_t WS_BIG_END = OFF_BIG + (size_t)BB*NN*NN;   // 172.7 MiB
static_assert(OFF_ID - OFF_X3 >= (size_t)4096*2048, "fallback dual dist fits");
static_assert(OFF_XCAT + (size_t)BN*768 <= WS_BIG_END, "xcat h/m/l fits in dist region");

typedef unsigned short u16;
typedef __attribute__((ext_vector_type(8))) short short8;
typedef __attribute__((ext_vector_type(8))) unsigned short ushort8;
typedef __attribute__((ext_vector_type(4))) float f32x4;

__device__ inline unsigned encf(float f){ unsigned u=__float_as_uint(f); return (u&0x80000000u)? ~u : (u|0x80000000u); }
__device__ inline float decf(unsigned e){ unsigned u=(e&0x80000000u)? (e&0x7fffffffu) : ~e; return __uint_as_float(u); }
__device__ inline float lrelu(float h){ return h>=0.f ? h : 0.2f*h; }
__device__ inline u16 bf16rne(float x){
  unsigned u = __float_as_uint(x);
  return (u16)((u + 0x7FFFu + ((u>>16)&1u)) >> 16);
}
__device__ inline float bf16f(u16 h){ return __uint_as_float((unsigned)h<<16); }
// exact 3-way split: x == h + m + l for normal fp32 (24 mantissa bits covered)
__device__ inline void bf16split3(float v, u16& h, u16& m, u16& l){
  h = bf16rne(v);  float r1 = v  - bf16f(h);
  m = bf16rne(r1); float r2 = r1 - bf16f(m);
  l = bf16rne(r2);
}

__device__ inline float readlane_f(float v, int sl){
  return __int_as_float(__builtin_amdgcn_readlane(__float_as_int(v), sl));
}

// Wave-cooperative sorted-top-20 insertion (cv known > theta on call).
// Tie-correct rank (equal values: lower index ranks first, matching lax.top_k).
// theta/cv via v_readlane (uniform); shfl_up for the shift (hidden by TLP at this occupancy).
#define INSERT_CAND(cv, ci) { \
  unsigned long long mge = __ballot((lv > cv) || (lv == cv && li < ci)); \
  int pos = __popcll(mge); \
  float upv = __shfl_up(lv, 1); \
  int   upi = __shfl_up(li, 1); \
  bool shift = (lane > pos) && (lane < KK); \
  lv = (lane == pos) ? cv : (shift ? upv : lv); \
  li = (lane == pos) ? ci : (shift ? upi : li); \
  theta = readlane_f(lv, KK-1); }

// Bitonic full sort of 64 (value desc, index asc on ties) across lanes; (v,vi) in registers.
#define BITONIC64_DESC(v, vi) { \
  _Pragma("unroll") \
  for(int k=2; k<=64; k<<=1){ \
    _Pragma("unroll") \
    for(int j=k>>1; j>=1; j>>=1){ \
      float ov = __shfl_xor(v, j); \
      int   oi = __shfl_xor(vi, j); \
      int partner = lane ^ j; \
      bool keepFirst = (((lane & k) == 0)) == (lane < partner); \
      bool before = (v > ov) || (v == ov && vi < oi); \
      if(keepFirst != before){ v = ov; vi = oi; } \
    } \
  } }

// ======== fragment-major tiled split layout ========
// split[rowGroup][kTile][lane=64][8]  (u16). lane l -> row = rg*16 + (l&15), k = kt*32 + (l>>4)*8.
// A wave's MFMA fragment load = base + lane*16B : one contiguous 1KB transaction.

// ---------------- prep: cat-transposed weights + W5T + W5 bf16 3-split (tiled) + enc ----------------
__global__ void prep_k(const float* W5, const float* W2, const float* W3, const float* W4,
                       float* W5T, float* WT2, float* WT3, float* WT4,
                       u16* w5h, u16* w5m, u16* w5l,
                       unsigned* mx, unsigned* mn){
  int i = blockIdx.x*256 + threadIdx.x;     // 262144
  { int o = i>>9, c = i&511; W5T[c*512+o] = W5[i]; }
  { // tiled split of W5 (B-side rows = output cols o, k = input c). KT=16.
    int rg = i>>13, kt = (i>>9)&15, l = (i>>3)&63, j = i&7;
    int o = rg*16 + (l&15);
    int c = kt*32 + ((l>>4)<<3) + j;
    u16 h,m,lo; bf16split3(W5[(size_t)o*512 + c], h, m, lo);
    w5h[i]=h; w5m[i]=m; w5l[i]=lo; }
  if(i < 65536){ int c = i>>9, o = i&511;   // W4: [256][256] -> cat [128][512]
    WT4[i] = (o<256) ? W4[(size_t)o*256 + c] : W4[(size_t)(o-256)*256 + 128 + c]; }
  if(i < 16384){ int c = i>>8, o = i&255;   // W3: [128][128] -> cat [64][256]
    WT3[i] = (o<128) ? W3[(size_t)o*128 + c] : W3[(size_t)(o-128)*128 + 64 + c]; }
  if(i <  8192){ int c = i>>7, o = i&127;   // W2: [64][128] -> cat [64][128]
    WT2[i] = (o<64) ? W2[(size_t)o*128 + c] : W2[(size_t)(o-64)*128 + 64 + c]; }
  if(i <  4096){ mx[i] = 0x007FFFFFu; mn[i] = 0xFF800000u; }
}

// ---------------- KNN ----------------
template<int C>
__launch_bounds__(256) __global__ void sqnorm_k(const float* X, float* xx){
  int i = blockIdx.x*256 + threadIdx.x;   // BN
  const float* r = X + (size_t)i*C;
  float s = 0.f;
  #pragma unroll
  for(int c=0;c<C;c++) s = fmaf(r[c], r[c], s);
  xx[i] = s;
}

// 3-way bf16 split of X [BN][C] into fragment-major tiled layout.
template<int C>
__launch_bounds__(256) __global__ void split_k(const float* __restrict__ X,
    u16* __restrict__ xh, u16* __restrict__ xm, u16* __restrict__ xl){
  constexpr int KT = C/32;
  const size_t t = (size_t)blockIdx.x*256 + threadIdx.x;   // BN*C/8 chunks
  const int l = (int)(t & 63);
  const size_t tile = t >> 6;               // rgG*KT + kt
  const int kt = (int)(tile & (KT-1));
  const size_t rgG = tile / KT;             // global row group (BN/16 total)
  const size_t row = rgG*16 + (l & 15);
  const int k = kt*32 + ((l>>4)<<3);
  const float* p = X + row*C + k;
  float4 v0 = *(const float4*)p;
  float4 v1 = *(const float4*)(p+4);
  float vs[8] = {v0.x,v0.y,v0.z,v0.w,v1.x,v1.y,v1.z,v1.w};
  ushort8 H,M,L;
  #pragma unroll
  for(int j=0;j<8;j++){ u16 h,m,lo; bf16split3(vs[j],h,m,lo); H[j]=h; M[j]=m; L[j]=lo; }
  *(ushort8*)(xh + t*8) = H;
  *(ushort8*)(xm + t*8) = M;
  *(ushort8*)(xl + t*8) = L;
}

#define FMA_ROW(I) \
  acc[I][0]=fmaf(a,b0v,acc[I][0]); acc[I][1]=fmaf(a,b1v,acc[I][1]); \
  acc[I][2]=fmaf(a,b2v,acc[I][2]); acc[I][3]=fmaf(a,b3v,acc[I][3]); \
  acc[I][4]=fmaf(a,b4v,acc[I][4]); acc[I][5]=fmaf(a,b5v,acc[I][5]); \
  acc[I][6]=fmaf(a,b6v,acc[I][6]); acc[I][7]=fmaf(a,b7v,acc[I][7]);

// fallback fp32 dist GEMM
template<int C>
__launch_bounds__(256) __global__ void gemm_dist_k(const float* __restrict__ X, const float* __restrict__ xx,
                                                   float* __restrict__ dist, int b0){
  constexpr int AST = 188;
  __shared__ __align__(16) float a_sh[16*AST];
  __shared__ __align__(16) float b_sh[16*AST];
  __shared__ float sxn[128], sxm[128];
  const int tid = threadIdx.x;
  const int b   = b0 + blockIdx.z;
  const int mtile = blockIdx.x*128;
  const int ntile = blockIdx.y*128;
  const int tn = tid & 15, tm = tid >> 4;
  const float* Xb  = X  + (size_t)b*NN*C;
  const float* xxb = xx + (size_t)b*NN;
  if(tid < 128) sxn[tid] = xxb[ntile + tid];
  else          sxm[tid-128] = xxb[mtile + tid-128];
  float acc[8][8];
  #pragma unroll
  for(int i=0;i<8;i++){
    #pragma unroll
    for(int j=0;j<8;j++) acc[i][j]=0.f;
  }
  for(int cc=0; cc<C; cc+=16){
    __syncthreads();
    #pragma unroll
    for(int s=0;s<2;s++){
      int ii = tid + 256*s; int r = ii>>2, q = ii&3;
      int pr = r + 4*(r>>3);
      float4 va = *(const float4*)&Xb[(size_t)(ntile + r)*C + cc + 4*q];
      a_sh[(4*q+0)*AST + pr]=va.x; a_sh[(4*q+1)*AST + pr]=va.y;
      a_sh[(4*q+2)*AST + pr]=va.z; a_sh[(4*q+3)*AST + pr]=va.w;
      float4 vb = *(const float4*)&Xb[(size_t)(mtile + r)*C + cc + 4*q];
      b_sh[(4*q+0)*AST + pr]=vb.x; b_sh[(4*q+1)*AST + pr]=vb.y;
      b_sh[(4*q+2)*AST + pr]=vb.z; b_sh[(4*q+3)*AST + pr]=vb.w;
    }
    __syncthreads();
    #pragma unroll
    for(int c=0;c<16;c++){
      float4 A0 = *(const float4*)&a_sh[c*AST + 12*tn];
      float4 A1 = *(const float4*)&a_sh[c*AST + 12*tn + 4];
      float4 B0 = *(const float4*)&b_sh[c*AST + 12*tm];
      float4 B1 = *(const float4*)&b_sh[c*AST + 12*tm + 4];
      float b0v=B0.x,b1v=B0.y,b2v=B0.z,b3v=B0.w,b4v=B1.x,b5v=B1.y,b6v=B1.z,b7v=B1.w;
      float a;
      a=A0.x; FMA_ROW(0)
      a=A0.y; FMA_ROW(1)
      a=A0.z; FMA_ROW(2)
      a=A0.w; FMA_ROW(3)
      a=A1.x; FMA_ROW(4)
      a=A1.y; FMA_ROW(5)
      a=A1.z; FMA_ROW(6)
      a=A1.w; FMA_ROW(7)
    }
  }
  float xnr[8], xmr[8];
  #pragma unroll
  for(int i=0;i<8;i++){ xnr[i]=sxn[tn*8+i]; xmr[i]=sxm[tm*8+i]; }
  const size_t rowb = (size_t)blockIdx.z*NN + ntile + tn*8;
  #pragma unroll
  for(int i=0;i<8;i++){
    float4 w0, w1;
    w0.x=(2.f*acc[i][0]-xnr[i])-xmr[0]; w0.y=(2.f*acc[i][1]-xnr[i])-xmr[1];
    w0.z=(2.f*acc[i][2]-xnr[i])-xmr[2]; w0.w=(2.f*acc[i][3]-xnr[i])-xmr[3];
    w1.x=(2.f*acc[i][4]-xnr[i])-xmr[4]; w1.y=(2.f*acc[i][5]-xnr[i])-xmr[5];
    w1.z=(2.f*acc[i][6]-xnr[i])-xmr[6]; w1.w=(2.f*acc[i][7]-xnr[i])-xmr[7];
    float* dp = dist + (rowb + i)*NN + mtile + tm*8;
    *(float4*)dp = w0;
    *(float4*)(dp+4) = w1;
  }
}

// big path: exact-fp32-quality dist via split-bf16 MFMA (6 products of 3-way split).
// Tiled fragment-major operands: every load = base + lane*16B (coalesced 1KB wave transaction).
template<int C>
__launch_bounds__(256) __global__ void mfma_dist_k(const u16* __restrict__ xh, const u16* __restrict__ xm,
    const u16* __restrict__ xl, const float* __restrict__ xx, float* __restrict__ dist){
  constexpr int KT = C/32;
  const int tid = threadIdx.x;
  const int l  = tid & 63, wv = tid >> 6;
  const int lg = l >> 4, lr = l & 15;
  const int b  = blockIdx.z;
  const int qrow0 = blockIdx.y*128 + (wv>>1)*64;   // query rows (A side, dist row)
  const int crow0 = blockIdx.x*128 + (wv&1)*64;    // candidate rows (B side, dist col)
  const size_t brg = (size_t)b*(NN/16);
  f32x4 acc[4][4];
  #pragma unroll
  for(int m=0;m<4;m++){
    #pragma unroll
    for(int n=0;n<4;n++) acc[m][n] = (f32x4){0.f,0.f,0.f,0.f};
  }
  const size_t abase = (brg + (qrow0>>4))*KT*512 + (size_t)l*8;
  const size_t bbase = (brg + (crow0>>4))*KT*512 + (size_t)l*8;
  for(int kt=0; kt<KT; kt++){
    short8 Ah[4], Am[4], Al[4], Bh[4], Bm[4], Bl[4];
    #pragma unroll
    for(int m=0;m<4;m++){
      size_t o = abase + (size_t)(m*KT + kt)*512;
      Ah[m] = *(const short8*)(xh + o);
      Am[m] = *(const short8*)(xm + o);
      Al[m] = *(const short8*)(xl + o);
    }
    #pragma unroll
    for(int n=0;n<4;n++){
      size_t o = bbase + (size_t)(n*KT + kt)*512;
      Bh[n] = *(const short8*)(xh + o);
      Bm[n] = *(const short8*)(xm + o);
      Bl[n] = *(const short8*)(xl + o);
    }
    #pragma unroll
    for(int m=0;m<4;m++){
      #pragma unroll
      for(int n=0;n<4;n++){
        acc[m][n] = __builtin_amdgcn_mfma_f32_16x16x32_bf16(Ah[m], Bh[n], acc[m][n], 0, 0, 0);
        acc[m][n] = __builtin_amdgcn_mfma_f32_16x16x32_bf16(Ah[m], Bm[n], acc[m][n], 0, 0, 0);
        acc[m][n] = __builtin_amdgcn_mfma_f32_16x16x32_bf16(Am[m], Bh[n], acc[m][n], 0, 0, 0);
        acc[m][n] = __builtin_amdgcn_mfma_f32_16x16x32_bf16(Ah[m], Bl[n], acc[m][n], 0, 0, 0);
        acc[m][n] = __builtin_amdgcn_mfma_f32_16x16x32_bf16(Al[m], Bh[n], acc[m][n], 0, 0, 0);
        acc[m][n] = __builtin_amdgcn_mfma_f32_16x16x32_bf16(Am[m], Bm[n], acc[m][n], 0, 0, 0);
      }
    }
  }
  const float* xxb = xx + (size_t)b*NN;
  float xxc[4];
  #pragma unroll
  for(int n=0;n<4;n++) xxc[n] = xxb[crow0 + n*16 + lr];
  #pragma unroll
  for(int m=0;m<4;m++){
    #pragma unroll
    for(int r=0;r<4;r++){
      int qr = qrow0 + m*16 + 4*lg + r;
      float xq = xxb[qr];
      float* dp = dist + ((size_t)b*NN + qr)*NN + crow0;
      #pragma unroll
      for(int n=0;n<4;n++) dp[n*16 + lr] = (2.f*acc[m][n][r] - xq) - xxc[n];
    }
  }
}

// Wave-cooperative top-20: max-of-4 bitonic warm start + slim insertions, float4 scan.
__launch_bounds__(256) __global__ void sel_k(const float* __restrict__ dist, int* __restrict__ id,
                                             int b0, int nrows){
  const int w = (blockIdx.x*256 + threadIdx.x) >> 6;
  const int lane = threadIdx.x & 63;
  if(w >= nrows) return;
  const float* dr = dist + (size_t)w*NN;
  // group 0: per-lane max of its 4 candidates (tie -> lowest j), bitonic those maxima,
  // then offer the remaining 3/lane through insertion (lane's max skipped via -INF).
  float4 c0 = *(const float4*)&dr[4*lane];
  float cd0[4] = {c0.x, c0.y, c0.z, c0.w};
  int jbest = 0; float v = cd0[0];
  #pragma unroll
  for(int j=1;j<4;j++){ if(cd0[j] > v){ v = cd0[j]; jbest = j; } }
  int vi = 4*lane + jbest;
  BITONIC64_DESC(v, vi)
  float lv = (lane < KK) ? v : -INFINITY;
  int   li = (lane < KK) ? vi : 0;
  float theta = readlane_f(lv, KK-1);
  #pragma unroll
  for(int j=0;j<4;j++){
    float cand = (j == jbest) ? -INFINITY : cd0[j];
    unsigned long long bal = __ballot(cand > theta);
    while(bal){
      int bpos = __ffsll((unsigned long long)bal) - 1;
      bal &= bal - 1;
      float cv = readlane_f(cand, bpos);
      if(cv > theta){
        int ci = 4*bpos + j;
        INSERT_CAND(cv, ci)
      }
    }
  }
  for(int ms=256; ms<NN; ms+=256){
    float4 c4 = *(const float4*)&dr[ms + 4*lane];
    #pragma unroll
    for(int j=0;j<4;j++){
      float cand = (j==0)?c4.x:(j==1)?c4.y:(j==2)?c4.z:c4.w;
      unsigned long long bal = __ballot(cand > theta);
      while(bal){
        int bpos = __ffsll((unsigned long long)bal) - 1;
        bal &= bal - 1;
        float cv = readlane_f(cand, bpos);
        if(cv > theta){
          int ci = ms + 4*bpos + j;
          INSERT_CAND(cv, ci)
        }
      }
    }
  }
  if(lane < KK) id[((size_t)b0*NN + w)*KK + lane] = li;
}

// L1 fused: inline C=3 distances + inline sqnorm, max-of-4 bitonic warm start.
__launch_bounds__(256) __global__ void sel3_k(const float* __restrict__ X, int* __restrict__ id){
  const int gw = (blockIdx.x*256 + threadIdx.x) >> 6;
  const int lane = threadIdx.x & 63;
  const int b = gw >> 11, n = gw & 2047;
  const float* Xb  = X + (size_t)b*NN*3;
  const float x0v = Xb[n*3], x1v = Xb[n*3+1], x2v = Xb[n*3+2];
  float xxn = 0.f;
  xxn = fmaf(x0v, x0v, xxn); xxn = fmaf(x1v, x1v, xxn); xxn = fmaf(x2v, x2v, xxn);
  float lv, theta; int li;
  {
    const float* p = Xb + (size_t)(4*lane)*3;
    float4 va = *(const float4*)p;
    float4 vb = *(const float4*)(p+4);
    float4 vc = *(const float4*)(p+8);
    float cx[4] = {va.x, va.w, vb.z, vc.y};
    float cy[4] = {va.y, vb.x, vb.w, vc.z};
    float cz[4] = {va.z, vb.y, vc.x, vc.w};
    float cd[4];
    #pragma unroll
    for(int j=0;j<4;j++){
      float s = 0.f;
      s = fmaf(x0v, cx[j], s); s = fmaf(x1v, cy[j], s); s = fmaf(x2v, cz[j], s);
      float xxm = 0.f;
      xxm = fmaf(cx[j], cx[j], xxm); xxm = fmaf(cy[j], cy[j], xxm); xxm = fmaf(cz[j], cz[j], xxm);
      cd[j] = (2.f*s - xxn) - xxm;
    }
    int jbest = 0; float v = cd[0];
    #pragma unroll
    for(int j=1;j<4;j++){ if(cd[j] > v){ v = cd[j]; jbest = j; } }
    int vi = 4*lane + jbest;
    BITONIC64_DESC(v, vi)
    lv = (lane < KK) ? v : -INFINITY;
    li = (lane < KK) ? vi : 0;
    theta = readlane_f(lv, KK-1);
    #pragma unroll
    for(int j=0;j<4;j++){
      float cand = (j == jbest) ? -INFINITY : cd[j];
      unsigned long long bal = __ballot(cand > theta);
      while(bal){
        int bpos = __ffsll((unsigned long long)bal) - 1;
        bal &= bal - 1;
        float cv = readlane_f(cand, bpos);
        if(cv > theta){
          int ci = 4*bpos + j;
          INSERT_CAND(cv, ci)
        }
      }
    }
  }
  for(int ms=256; ms<NN; ms+=256){
    const float* p = Xb + (size_t)(ms + 4*lane)*3;
    float4 va = *(const float4*)p;
    float4 vb = *(const float4*)(p+4);
    float4 vc = *(const float4*)(p+8);
    float cx[4] = {va.x, va.w, vb.z, vc.y};
    float cy[4] = {va.y, vb.x, vb.w, vc.z};
    float cz[4] = {va.z, vb.y, vc.x, vc.w};
    float cd[4];
    #pragma unroll
    for(int j=0;j<4;j++){
      float s = 0.f;
      s = fmaf(x0v, cx[j], s); s = fmaf(x1v, cy[j], s); s = fmaf(x2v, cz[j], s);
      float xxm = 0.f;
      xxm = fmaf(cx[j], cx[j], xxm); xxm = fmaf(cy[j], cy[j], xxm); xxm = fmaf(cz[j], cz[j], xxm);
      cd[j] = (2.f*s - xxn) - xxm;
    }
    #pragma unroll
    for(int j=0;j<4;j++){
      float cand = cd[j];
      unsigned long long bal = __ballot(cand > theta);
      while(bal){
        int bpos = __ffsll((unsigned long long)bal) - 1;
        bal &= bal - 1;
        float cv = readlane_f(cand, bpos);
        if(cv > theta){
          int ci = ms + 4*bpos + j;
          INSERT_CAND(cv, ci)
        }
      }
    }
  }
  if(lane < KK) id[(size_t)gw*KK + lane] = li;
}

// ---------------- qp ----------------
// L1: writes interleaved qp[row][128]: q at 0..63, p at 64..127
__launch_bounds__(256) __global__ void qp3_k(const float* X, const float* W, float* qp){
  const int t   = blockIdx.x*256 + threadIdx.x;
  const int row = t >> 3;
  const int c0  = (t & 7) * 8;
  float xn[3];
  #pragma unroll
  for(int c=0;c<3;c++) xn[c] = X[(size_t)row*3 + c];
  for(int oi=c0; oi<c0+8; oi++){
    const float* w = W + (size_t)oi*6;
    float aq=0.f, ap=0.f;
    #pragma unroll
    for(int c=0;c<3;c++){ aq = fmaf(xn[c], w[c], aq); ap = fmaf(xn[c], w[3+c], ap); }
    qp[(size_t)row*128 + oi]      = aq;
    qp[(size_t)row*128 + 64 + oi] = ap;
  }
}

// Tiled qp GEMM (big path): C[BN x W2C] = X[BN x CIN] * WTcat[CIN x W2C].
template<int CIN, int W2C>
__launch_bounds__(256) __global__ void qp_gemm_k(const float* __restrict__ X, const float* __restrict__ WT,
                                                 float* __restrict__ qp){
  constexpr int ASTA = 92;    // 64 rows, pad 4 per 8: max pr = 63+28 = 91
  constexpr int ASTB = 188;
  __shared__ __align__(16) float a_sh[16*ASTA];
  __shared__ __align__(16) float b_sh[16*ASTB];
  const int tid = threadIdx.x;
  const int otile = blockIdx.x*128;
  const int rtile = blockIdx.y*64;
  const int tn = tid & 15, tm = tid >> 4;
  const int aoff = 4*tn + 4*(tn>>1);   // padded offset of row 4*tn
  float acc[4][8];
  #pragma unroll
  for(int i=0;i<4;i++){
    #pragma unroll
    for(int j=0;j<8;j++) acc[i][j]=0.f;
  }
  for(int cc=0; cc<CIN; cc+=16){
    __syncthreads();
    { int r = tid>>2, q = tid&3;          // 64 rows x 16 c = 256 float4, 1/thread
      int pr = r + 4*(r>>3);
      float4 va = *(const float4*)&X[(size_t)(rtile + r)*CIN + cc + 4*q];
      a_sh[(4*q+0)*ASTA + pr]=va.x; a_sh[(4*q+1)*ASTA + pr]=va.y;
      a_sh[(4*q+2)*ASTA + pr]=va.z; a_sh[(4*q+3)*ASTA + pr]=va.w; }
    #pragma unroll
    for(int s=0;s<2;s++){                 // 16 c x 128 cols = 512 float4, 2/thread
      int ii = tid + 256*s;
      int cl = ii>>5, o4 = ii&31;
      float4 vb = *(const float4*)&WT[(size_t)(cc+cl)*W2C + otile + 4*o4];
      *(float4*)&b_sh[cl*ASTB + 4*o4 + 4*(o4>>1)] = vb;
    }
    __syncthreads();
    #pragma unroll
    for(int c=0;c<16;c++){
      float4 A0 = *(const float4*)&a_sh[c*ASTA + aoff];
      float4 B0 = *(const float4*)&b_sh[c*ASTB + 12*tm];
      float4 B1 = *(const float4*)&b_sh[c*ASTB + 12*tm + 4];
      float b0v=B0.x,b1v=B0.y,b2v=B0.z,b3v=B0.w,b4v=B1.x,b5v=B1.y,b6v=B1.z,b7v=B1.w;
      float a;
      a=A0.x; FMA_ROW(0)
      a=A0.y; FMA_ROW(1)
      a=A0.z; FMA_ROW(2)
      a=A0.w; FMA_ROW(3)
    }
  }
  #pragma unroll
  for(int i=0;i<4;i++){
    float* dp = qp + (size_t)(rtile + tn*4 + i)*W2C + otile + tm*8;
    *(float4*)dp     = make_float4(acc[i][0],acc[i][1],acc[i][2],acc[i][3]);
    *(float4*)(dp+4) = make_float4(acc[i][4],acc[i][5],acc[i][6],acc[i][7]);
  }
}

// Gather from interleaved qp[row][2*COUT] (q | p); base = p - q computed here (bit-exact).
template<int COUT>
__launch_bounds__(256) __global__ void gather_qp_k(const float* __restrict__ qp, const int* __restrict__ idx,
    const float* g, const float* bb, float* out){
  const int t  = blockIdx.x*256 + threadIdx.x;   // BN*COUT
  const int o  = t % COUT;
  const int bn = t / COUT;
  const int b  = bn >> 11;
  const int* id = idx + (size_t)bn*KK;
  float qv = qp[(size_t)bn*(2*COUT) + o];
  float pv = qp[(size_t)bn*(2*COUT) + COUT + o];
  float base = pv - qv;
  float mx = -INFINITY, mn = INFINITY;
  #pragma unroll
  for(int k=0;k<KK;k++){
    int ik = id[k];
    float v = qp[((size_t)((b<<11) + ik))*(2*COUT) + o];
    mx = fmaxf(mx, v); mn = fminf(mn, v);
  }
  float a  = g[o] * RSQ;
  float bo = bb[o];
  out[(size_t)bn*COUT + o] = lrelu((a >= 0.f ? a*(mx+base) : a*(mn+base)) + bo);
}

// ---- fallback chunked qp (cat weight layout) + chunked gather ----
template<int CIN, int COUT>
__launch_bounds__(256) __global__ void qp64T_k(const float* __restrict__ X, const float* __restrict__ WT,
                                               int cb, float* __restrict__ q, float* __restrict__ bs){
  const int t   = blockIdx.x*256 + threadIdx.x;
  const int row = t >> 3;
  const int o0  = cb + (t & 7) * 8;
  float xn[CIN];
  #pragma unroll
  for(int c=0;c<CIN;c+=4){ float4 v = *(const float4*)(X + (size_t)row*CIN + c);
    xn[c]=v.x; xn[c+1]=v.y; xn[c+2]=v.z; xn[c+3]=v.w; }
  float aq[8], ap[8];
  #pragma unroll
  for(int j=0;j<8;j++){ aq[j]=0.f; ap[j]=0.f; }
  #pragma unroll 4
  for(int c=0;c<CIN;c++){
    float xc = xn[c];
    float4 wa0 = *(const float4*)&WT[(size_t)c*(2*COUT) + o0];
    float4 wa1 = *(const float4*)&WT[(size_t)c*(2*COUT) + o0 + 4];
    float4 wb0 = *(const float4*)&WT[(size_t)c*(2*COUT) + COUT + o0];
    float4 wb1 = *(const float4*)&WT[(size_t)c*(2*COUT) + COUT + o0 + 4];
    aq[0]=fmaf(xc,wa0.x,aq[0]); aq[1]=fmaf(xc,wa0.y,aq[1]); aq[2]=fmaf(xc,wa0.z,aq[2]); aq[3]=fmaf(xc,wa0.w,aq[3]);
    aq[4]=fmaf(xc,wa1.x,aq[4]); aq[5]=fmaf(xc,wa1.y,aq[5]); aq[6]=fmaf(xc,wa1.z,aq[6]); aq[7]=fmaf(xc,wa1.w,aq[7]);
    ap[0]=fmaf(xc,wb0.x,ap[0]); ap[1]=fmaf(xc,wb0.y,ap[1]); ap[2]=fmaf(xc,wb0.z,ap[2]); ap[3]=fmaf(xc,wb0.w,ap[3]);
    ap[4]=fmaf(xc,wb1.x,ap[4]); ap[5]=fmaf(xc,wb1.y,ap[5]); ap[6]=fmaf(xc,wb1.z,ap[6]); ap[7]=fmaf(xc,wb1.w,ap[7]);
  }
  float* qpp = q  + (size_t)row*64 + (o0-cb);
  float* bpp = bs + (size_t)row*64 + (o0-cb);
  *(float4*)qpp     = make_float4(aq[0],aq[1],aq[2],aq[3]);
  *(float4*)(qpp+4) = make_float4(aq[4],aq[5],aq[6],aq[7]);
  *(float4*)bpp     = make_float4(ap[0]-aq[0],ap[1]-aq[1],ap[2]-aq[2],ap[3]-aq[3]);
  *(float4*)(bpp+4) = make_float4(ap[4]-aq[4],ap[5]-aq[5],ap[6]-aq[6],ap[7]-aq[7]);
}

template<int CFULL>
__launch_bounds__(256) __global__ void gather_chunk_k(const float* q, const float* bs, const int* idx,
    const float* g, const float* bb, int cb, float* out){
  const int t  = blockIdx.x*256 + threadIdx.x;
  const int o  = t & 63;
  const int bn = t >> 6;
  const int b  = bn >> 11;
  const int* id = idx + (size_t)bn*KK;
  float base = bs[t];
  float mx = -INFINITY, mn = INFINITY;
  #pragma unroll
  for(int k=0;k<KK;k++){
    int ik = id[k];
    float v = q[((size_t)((b<<11) + ik))*64 + o];
    mx = fmaxf(mx, v); mn = fminf(mn, v);
  }
  float a  = g[cb+o] * RSQ;
  float bo = bb[cb+o];
  out[(size_t)bn*CFULL + cb + o] = lrelu((a >= 0.f ? a*(mx+base) : a*(mn+base)) + bo);
}

// ---------------- head (fallback): fp32 GEMM-tiled cat x W5T with fused max/min ----------------
__launch_bounds__(256) __global__ void w5gemm_k(const float* __restrict__ x1, const float* __restrict__ x2,
    const float* __restrict__ x3, const float* __restrict__ x4,
    const float* __restrict__ W5T, unsigned* mxe, unsigned* mne){
  constexpr int ASTA = 92;
  constexpr int ASTB = 188;
  __shared__ __align__(16) float a_sh[16*ASTA];
  __shared__ __align__(16) float b_sh[16*ASTB];
  const int tid = threadIdx.x;
  const int otile = blockIdx.x*128;
  const int rtile = blockIdx.y*64;
  const int b     = blockIdx.z;
  const int tn = tid & 15, tm = tid >> 4;
  const int aoff = 4*tn + 4*(tn>>1);
  const size_t row0 = (size_t)b*NN + rtile;
  float acc[4][8];
  #pragma unroll
  for(int i=0;i<4;i++){
    #pragma unroll
    for(int j=0;j<8;j++) acc[i][j]=0.f;
  }
  for(int cc=0; cc<512; cc+=16){
    const float* src; int stride, coff;
    if(cc<64)      { src=x1; stride=64;  coff=cc; }
    else if(cc<128){ src=x2; stride=64;  coff=cc-64; }
    else if(cc<256){ src=x3; stride=128; coff=cc-128; }
    else           { src=x4; stride=256; coff=cc-256; }
    __syncthreads();
    { int r = tid>>2, q = tid&3;
      int pr = r + 4*(r>>3);
      float4 va = *(const float4*)&src[(row0 + r)*stride + coff + 4*q];
      a_sh[(4*q+0)*ASTA + pr]=va.x; a_sh[(4*q+1)*ASTA + pr]=va.y;
      a_sh[(4*q+2)*ASTA + pr]=va.z; a_sh[(4*q+3)*ASTA + pr]=va.w; }
    #pragma unroll
    for(int s=0;s<2;s++){
      int ii = tid + 256*s;
      int cl = ii>>5, o4 = ii&31;
      float4 vb = *(const float4*)&W5T[(size_t)(cc+cl)*512 + otile + 4*o4];
      *(float4*)&b_sh[cl*ASTB + 4*o4 + 4*(o4>>1)] = vb;
    }
    __syncthreads();
    #pragma unroll
    for(int c=0;c<16;c++){
      float4 A0 = *(const float4*)&a_sh[c*ASTA + aoff];
      float4 B0 = *(const float4*)&b_sh[c*ASTB + 12*tm];
      float4 B1 = *(const float4*)&b_sh[c*ASTB + 12*tm + 4];
      float b0v=B0.x,b1v=B0.y,b2v=B0.z,b3v=B0.w,b4v=B1.x,b5v=B1.y,b6v=B1.z,b7v=B1.w;
      float a;
      a=A0.x; FMA_ROW(0)
      a=A0.y; FMA_ROW(1)
      a=A0.z; FMA_ROW(2)
      a=A0.w; FMA_ROW(3)
    }
  }
  #pragma unroll
  for(int j=0;j<8;j++){
    float M=-INFINITY, m=INFINITY;
    #pragma unroll
    for(int i=0;i<4;i++){ M=fmaxf(M,acc[i][j]); m=fminf(m,acc[i][j]); }
    #pragma unroll
    for(int d=1; d<16; d<<=1){
      M = fmaxf(M, __shfl_xor(M, d));
      m = fminf(m, __shfl_xor(m, d));
    }
    if(tn == 0){
      int o = otile + tm*8 + j;
      atomicMax(&mxe[b*512+o], encf(M));
      atomicMin(&mne[b*512+o], encf(m));
    }
  }
}

// ---------------- head (big): split-bf16 MFMA ----------------
// xcat 3-split into fragment-major tiled layout (KT=16, row space = BN).
__launch_bounds__(256) __global__ void cvt_k(const float* __restrict__ x1, const float* __restrict__ x2,
    const float* __restrict__ x3, const float* __restrict__ x4,
    u16* __restrict__ xh, u16* __restrict__ xm, u16* __restrict__ xl){
  const size_t t = (size_t)blockIdx.x*256 + threadIdx.x;   // BN*512/8 chunks
  const int l = (int)(t & 63);
  const size_t tile = t >> 6;           // rgG*16 + kt
  const int kt = (int)(tile & 15);
  const size_t rgG = tile >> 4;
  const size_t row = rgG*16 + (l & 15);
  const int col = kt*32 + ((l>>4)<<3);
  const float* src; int stride, coff;
  if(col<64)      { src=x1; stride=64;  coff=col; }
  else if(col<128){ src=x2; stride=64;  coff=col-64; }
  else if(col<256){ src=x3; stride=128; coff=col-128; }
  else            { src=x4; stride=256; coff=col-256; }
  const float* p = src + row*stride + coff;
  float4 v0 = *(const float4*)p;
  float4 v1 = *(const float4*)(p+4);
  float vs[8] = {v0.x,v0.y,v0.z,v0.w,v1.x,v1.y,v1.z,v1.w};
  ushort8 H, M, L;
  #pragma unroll
  for(int j=0;j<8;j++){ u16 h,m,lo; bf16split3(vs[j],h,m,lo); H[j]=h; M[j]=m; L[j]=lo; }
  *(ushort8*)(xh + t*8) = H;
  *(ushort8*)(xm + t*8) = M;
  *(ushort8*)(xl + t*8) = L;
}

// C[16384x512] = xcat * W5^T via 6 bf16 MFMA products (fp32-exact to ~2^-27), fp32 accum.
__launch_bounds__(256) __global__ void w5mfma_k(const u16* __restrict__ xh, const u16* __restrict__ xm,
    const u16* __restrict__ xl,
    const u16* __restrict__ wh, const u16* __restrict__ wm, const u16* __restrict__ wl,
    unsigned* mxe, unsigned* mne){
  const int tid = threadIdx.x;
  const int l  = tid & 63, wv = tid >> 6;
  const int lg = l >> 4, lr = l & 15;
  const int row0 = blockIdx.y*128 + (wv>>1)*64;   // M base of this wave (global BN rows)
  const int col0 = blockIdx.x*128 + (wv&1)*64;    // N base of this wave
  const int b = blockIdx.y >> 4;                  // 16 M-blocks per batch
  f32x4 acc[4][4];
  #pragma unroll
  for(int m=0;m<4;m++){
    #pragma unroll
    for(int n=0;n<4;n++) acc[m][n] = (f32x4){0.f,0.f,0.f,0.f};
  }
  const size_t abase = (size_t)(row0>>4)*16*512 + (size_t)l*8;
  const size_t bbase = (size_t)(col0>>4)*16*512 + (size_t)l*8;
  for(int kt=0; kt<16; kt++){
    short8 Ah[4], Am[4], Al[4], Bh[4], Bm[4], Bl[4];
    #pragma unroll
    for(int m=0;m<4;m++){
      size_t o = abase + (size_t)(m*16 + kt)*512;
      Ah[m] = *(const short8*)(xh + o);
      Am[m] = *(const short8*)(xm + o);
      Al[m] = *(const short8*)(xl + o);
    }
    #pragma unroll
    for(int n=0;n<4;n++){
      size_t o = bbase + (size_t)(n*16 + kt)*512;
      Bh[n] = *(const short8*)(wh + o);
      Bm[n] = *(const short8*)(wm + o);
      Bl[n] = *(const short8*)(wl + o);
    }
    #pragma unroll
    for(int m=0;m<4;m++){
      #pragma unroll
      for(int n=0;n<4;n++){
        acc[m][n] = __builtin_amdgcn_mfma_f32_16x16x32_bf16(Ah[m], Bh[n], acc[m][n], 0, 0, 0);
        acc[m][n] = __builtin_amdgcn_mfma_f32_16x16x32_bf16(Ah[m], Bm[n], acc[m][n], 0, 0, 0);
        acc[m][n] = __builtin_amdgcn_mfma_f32_16x16x32_bf16(Am[m], Bh[n], acc[m][n], 0, 0, 0);
        acc[m][n] = __builtin_amdgcn_mfma_f32_16x16x32_bf16(Ah[m], Bl[n], acc[m][n], 0, 0, 0);
        acc[m][n] = __builtin_amdgcn_mfma_f32_16x16x32_bf16(Al[m], Bh[n], acc[m][n], 0, 0, 0);
        acc[m][n] = __builtin_amdgcn_mfma_f32_16x16x32_bf16(Am[m], Bm[n], acc[m][n], 0, 0, 0);
      }
    }
  }
  #pragma unroll
  for(int n=0;n<4;n++){
    float M = -INFINITY, mnv = INFINITY;
    #pragma unroll
    for(int m=0;m<4;m++){
      #pragma unroll
      for(int r=0;r<4;r++){ float v = acc[m][n][r]; M = fmaxf(M, v); mnv = fminf(mnv, v); }
    }
    M   = fmaxf(M,   __shfl_xor(M, 16));   M   = fmaxf(M,   __shfl_xor(M, 32));
    mnv = fminf(mnv, __shfl_xor(mnv, 16)); mnv = fminf(mnv, __shfl_xor(mnv, 32));
    if(lg == 0){
      int o = col0 + n*16 + lr;
      atomicMax(&mxe[b*512+o], encf(M));
      atomicMin(&mne[b*512+o], encf(mnv));
    }
  }
}

__launch_bounds__(256) __global__ void final_k(const unsigned* mxe, const unsigned* mne,
    const float* g5, const float* b5, const float* Wemb, float* out){
  const int b = blockIdx.x, t = threadIdx.x;
  __shared__ float h[512];
  for(int o=t; o<512; o+=256){
    float mx = decf(mxe[b*512+o]);
    float mn = decf(mne[b*512+o]);
    float a  = g5[o] * RSQ;
    float bo = b5[o];
    float hv = lrelu((a >= 0.f ? a*mx : a*mn) + bo);
    h[o] = hv;
    out[b*512+o] = hv;
  }
  __syncthreads();
  const float* wr = Wemb + (size_t)t*512;
  float s = 0.f;
  for(int o=0;o<512;o+=4){
    float4 w4 = *(const float4*)(wr+o);
    s = fmaf(h[o],w4.x, fmaf(h[o+1],w4.y, fmaf(h[o+2],w4.z, fmaf(h[o+3],w4.w, s))));
  }
  out[4096 + b*256 + t] = s;
}

// ---------------- launch ----------------
extern "C" void kernel_launch(void* const* d_in, const int* in_sizes, int n_in,
                              void* d_out, int out_size, void* d_ws, size_t ws_size,
                              hipStream_t stream) {
  if (ws_size < WS_END * sizeof(float)) return;
  const bool big = ws_size >= WS_BIG_END * sizeof(float);   // deterministic per call

  const float* x0   = (const float*)d_in[0];
  const float* W1   = (const float*)d_in[1];
  const float* g1   = (const float*)d_in[2];
  const float* b1   = (const float*)d_in[3];
  const float* W2   = (const float*)d_in[4];
  const float* g2   = (const float*)d_in[5];
  const float* b2   = (const float*)d_in[6];
  const float* W3   = (const float*)d_in[7];
  const float* g3   = (const float*)d_in[8];
  const float* b3   = (const float*)d_in[9];
  const float* W4   = (const float*)d_in[10];
  const float* g4   = (const float*)d_in[11];
  const float* b4   = (const float*)d_in[12];
  const float* W5   = (const float*)d_in[13];
  const float* g5   = (const float*)d_in[14];
  const float* b5   = (const float*)d_in[15];
  const float* Wemb = (const float*)d_in[16];

  float* ws = (float*)d_ws;
  float* xx = ws + OFF_XX;
  float* x1 = ws + OFF_X1;  float* x2 = ws + OFF_X2;
  float* x3 = ws + OFF_X3;  float* x4 = ws + OFF_X4;
  float* qpS = ws + OFF_SC;               // L1 qp (width 128) + fallback chunked q/bs
  float* bsS = ws + OFF_SC + (size_t)BN*64;
  int*   id = (int*)(ws + OFF_ID);
  float* W5Tf = ws + OFF_W5T;
  unsigned* mxe = (unsigned*)(ws + OFF_MX);
  unsigned* mne = (unsigned*)(ws + OFF_MN);
  float* WT2 = ws + OFF_WT2;
  float* WT3 = ws + OFF_WT3;
  float* WT4 = ws + OFF_WT4;
  float* distD = ws + OFF_X3;   // fallback dual-batch
  float* distS = ws + OFF_X4;   // fallback single-batch
  float* distB = ws + OFF_BIG;  // big: 8-batch dist, then reused as qp buffer / bf16 xcat
  u16* w5h = (u16*)(ws + OFF_SC + (size_t)BN*128);   // SC tail (free in both paths): 3x256KB
  u16* w5m = w5h + 512*512;
  u16* w5l = w5m + 512*512;
  float* out = (float*)d_out;

  prep_k<<<1024,256,0,stream>>>(W5, W2, W3, W4, W5Tf, WT2, WT3, WT4, w5h, w5m, w5l, mxe, mne);

  // layer 1 (3 -> 64)
  sel3_k<<<BN*64/256,256,0,stream>>>(x0, id);
  qp3_k<<<BN*8/256,256,0,stream>>>(x0, W1, qpS);
  gather_qp_k<64><<<BN*64/256,256,0,stream>>>(qpS, id, g1, b1, x1);

  if(big){
    float* qpB = distB;                      // reuse dist region post-sel
    // split scratch lives in x4 region (dead until layer-4 gather)
    u16* sh = (u16*)x4;
    // layer 2 (CIN=64 -> COUT=64, qp width 128)
    { u16* sm = sh + (size_t)BN*64; u16* sl = sm + (size_t)BN*64;
      sqnorm_k<64><<<BN/256,256,0,stream>>>(x1, xx);
      split_k<64><<<BN*64/8/256,256,0,stream>>>(x1, sh, sm, sl);
      mfma_dist_k<64><<<dim3(16,16,8),256,0,stream>>>(sh, sm, sl, xx, distB);
      sel_k<<<(8*NN)/4,256,0,stream>>>(distB, id, 0, 8*NN);
      qp_gemm_k<64,128><<<dim3(1,BN/64),256,0,stream>>>(x1, WT2, qpB);
      gather_qp_k<64><<<BN*64/256,256,0,stream>>>(qpB, id, g2, b2, x2); }
    // layer 3 (64 -> 128, qp width 256)
    { u16* sm = sh + (size_t)BN*64; u16* sl = sm + (size_t)BN*64;
      sqnorm_k<64><<<BN/256,256,0,stream>>>(x2, xx);
      split_k<64><<<BN*64/8/256,256,0,stream>>>(x2, sh, sm, sl);
      mfma_dist_k<64><<<dim3(16,16,8),256,0,stream>>>(sh, sm, sl, xx, distB);
      sel_k<<<(8*NN)/4,256,0,stream>>>(distB, id, 0, 8*NN);
      qp_gemm_k<64,256><<<dim3(2,BN/64),256,0,stream>>>(x2, WT3, qpB);
      gather_qp_k<128><<<BN*128/256,256,0,stream>>>(qpB, id, g3, b3, x3); }
    // layer 4 (128 -> 256, qp width 512)
    { u16* sm = sh + (size_t)BN*128; u16* sl = sm + (size_t)BN*128;
      sqnorm_k<128><<<BN/256,256,0,stream>>>(x3, xx);
      split_k<128><<<BN*128/8/256,256,0,stream>>>(x3, sh, sm, sl);
      mfma_dist_k<128><<<dim3(16,16,8),256,0,stream>>>(sh, sm, sl, xx, distB);
      sel_k<<<(8*NN)/4,256,0,stream>>>(distB, id, 0, 8*NN);
      qp_gemm_k<128,512><<<dim3(4,BN/64),256,0,stream>>>(x3, WT4, qpB);
      gather_qp_k<256><<<BN*256/256,256,0,stream>>>(qpB, id, g4, b4, x4); }
    // head: bf16 3-split (tiled) + 6-product MFMA
    u16* xh = (u16*)(ws + OFF_XCAT);
    u16* xm = xh + (size_t)BN*512;
    u16* xl = xm + (size_t)BN*512;
    cvt_k<<<BN*512/8/256,256,0,stream>>>(x1, x2, x3, x4, xh, xm, xl);
    w5mfma_k<<<dim3(4,128),256,0,stream>>>(xh, xm, xl, w5h, w5m, w5l, mxe, mne);
  } else {
    // fallback: chunked (R12 structure, cat weight layout)
    sqnorm_k<64><<<BN/256,256,0,stream>>>(x1, xx);
    for(int r=0;r<4;r++){
      gemm_dist_k<64><<<dim3(16,16,2),256,0,stream>>>(x1, xx, distD, 2*r);
      sel_k<<<(2*NN)/4,256,0,stream>>>(distD, id, 2*r, 2*NN);
    }
    qp64T_k<64,64><<<BN*8/256,256,0,stream>>>(x1, WT2, 0, qpS, bsS);
    gather_chunk_k<64><<<BN*64/256,256,0,stream>>>(qpS, bsS, id, g2, b2, 0, x2);

    sqnorm_k<64><<<BN/256,256,0,stream>>>(x2, xx);
    for(int r=0;r<4;r++){
      gemm_dist_k<64><<<dim3(16,16,2),256,0,stream>>>(x2, xx, distD, 2*r);
      sel_k<<<(2*NN)/4,256,0,stream>>>(distD, id, 2*r, 2*NN);
    }
    for(int cb=0; cb<128; cb+=64){
      qp64T_k<64,128><<<BN*8/256,256,0,stream>>>(x2, WT3, cb, qpS, bsS);
      gather_chunk_k<128><<<BN*64/256,256,0,stream>>>(qpS, bsS, id, g3, b3, cb, x3);
    }

    sqnorm_k<128><<<BN/256,256,0,stream>>>(x3, xx);
    for(int r=0;r<8;r++){
      gemm_dist_k<128><<<dim3(16,16,1),256,0,stream>>>(x3, xx, distS, r);
      sel_k<<<NN/4,256,0,stream>>>(distS, id, r, NN);
    }
    for(int cb=0; cb<256; cb+=64){
      qp64T_k<128,256><<<BN*8/256,256,0,stream>>>(x3, WT4, cb, qpS, bsS);
      gather_chunk_k<256><<<BN*64/256,256,0,stream>>>(qpS, bsS, id, g4, b4, cb, x4);
    }
    w5gemm_k<<<dim3(4,32,8),256,0,stream>>>(x1, x2, x3, x4, W5Tf, mxe, mne);
  }

  final_k<<<BB,256,0,stream>>>(mxe, mne, g5, b5, Wemb, out);
}

// Round 10
// 600.755 us; speedup vs baseline: 1.1351x; 1.0286x over previous
//
#include <hip/hip_runtime.h>
#include <hip/hip_bf16.h>

#define BB 8
#define NN 2048
#define KK 20
#define BN (BB*NN)
#define RSQ 0.99999500003749969f   // 1/sqrt(1+1e-5)

// ---------------- workspace layout (float-slot units), 44.7 MiB baseline ----------------
constexpr size_t OFF_XX  = 0;                          // BN
constexpr size_t OFF_X1  = OFF_XX  + BN;               // BN*64
constexpr size_t OFF_X2  = OFF_X1  + (size_t)BN*64;    // BN*64
constexpr size_t OFF_X3  = OFF_X2  + (size_t)BN*64;    // BN*128
constexpr size_t OFF_X4  = OFF_X3  + (size_t)BN*128;   // BN*256 (split-scratch pre-gather)
constexpr size_t OFF_SC  = OFF_X4  + (size_t)BN*256;   // BN*160 (L1 qp + fallback chunked qp + W5 bf16 tail)
constexpr size_t OFF_ID  = OFF_SC  + (size_t)BN*160;   // int BN*20
constexpr size_t OFF_W5T = OFF_ID  + (size_t)BN*20;    // 512*512 (big path: tiled WT splits live here)
constexpr size_t OFF_MX  = OFF_W5T + 512*512;
constexpr size_t OFF_MN  = OFF_MX  + BB*512;
constexpr size_t OFF_WT2 = OFF_MN  + BB*512;           // cat [64][128]
constexpr size_t OFF_WT3 = OFF_WT2 + 8192;             // cat [64][256]
constexpr size_t OFF_WT4 = OFF_WT3 + 16384;            // cat [128][512]
constexpr size_t WS_END  = OFF_WT4 + 65536;            // 11,714,560 floats
// big region (probed at runtime): dist chunk (4 batches) + qp buffer + bf16 xcat post-sel
constexpr size_t OFF_BIG = WS_END;
constexpr size_t OFF_XCAT = OFF_BIG + (size_t)16*1024*1024;  // bf16 xcat h/m/l (dist region tail, post-KNN)
constexpr size_t WS_BIG_END = OFF_BIG + (size_t)BB*NN*NN;   // 172.7 MiB
static_assert(OFF_ID - OFF_X3 >= (size_t)4096*2048, "fallback dual dist fits");
static_assert(OFF_XCAT + (size_t)BN*768 <= WS_BIG_END, "xcat h/m/l fits in dist region");

typedef unsigned short u16;
typedef __attribute__((ext_vector_type(8))) short short8;
typedef __attribute__((ext_vector_type(8))) unsigned short ushort8;
typedef __attribute__((ext_vector_type(4))) float f32x4;

// tiled WT split offsets (u16 units) within the W5T region (big path only)
constexpr size_t WTS_2H = 0,      WTS_2M = 8192,   WTS_2L = 16384;
constexpr size_t WTS_3H = 24576,  WTS_3M = 40960,  WTS_3L = 57344;
constexpr size_t WTS_4H = 73728,  WTS_4M = 139264, WTS_4L = 204800;   // end 270336 u16 <= 524288

__device__ inline unsigned encf(float f){ unsigned u=__float_as_uint(f); return (u&0x80000000u)? ~u : (u|0x80000000u); }
__device__ inline float decf(unsigned e){ unsigned u=(e&0x80000000u)? (e&0x7fffffffu) : ~e; return __uint_as_float(u); }
__device__ inline float lrelu(float h){ return h>=0.f ? h : 0.2f*h; }
__device__ inline u16 bf16rne(float x){
  unsigned u = __float_as_uint(x);
  return (u16)((u + 0x7FFFu + ((u>>16)&1u)) >> 16);
}
__device__ inline float bf16f(u16 h){ return __uint_as_float((unsigned)h<<16); }
// exact 3-way split: x == h + m + l for normal fp32 (24 mantissa bits covered)
__device__ inline void bf16split3(float v, u16& h, u16& m, u16& l){
  h = bf16rne(v);  float r1 = v  - bf16f(h);
  m = bf16rne(r1); float r2 = r1 - bf16f(m);
  l = bf16rne(r2);
}

__device__ inline float readlane_f(float v, int sl){
  return __int_as_float(__builtin_amdgcn_readlane(__float_as_int(v), sl));
}

// Wave-cooperative sorted-top-20 insertion (cv known > theta on call).
#define INSERT_CAND(cv, ci) { \
  unsigned long long mge = __ballot((lv > cv) || (lv == cv && li < ci)); \
  int pos = __popcll(mge); \
  float upv = __shfl_up(lv, 1); \
  int   upi = __shfl_up(li, 1); \
  bool shift = (lane > pos) && (lane < KK); \
  lv = (lane == pos) ? cv : (shift ? upv : lv); \
  li = (lane == pos) ? ci : (shift ? upi : li); \
  theta = readlane_f(lv, KK-1); }

// Bitonic full sort of 64 (value desc, index asc on ties) across lanes; (v,vi) in registers.
#define BITONIC64_DESC(v, vi) { \
  _Pragma("unroll") \
  for(int k=2; k<=64; k<<=1){ \
    _Pragma("unroll") \
    for(int j=k>>1; j>=1; j>>=1){ \
      float ov = __shfl_xor(v, j); \
      int   oi = __shfl_xor(vi, j); \
      int partner = lane ^ j; \
      bool keepFirst = (((lane & k) == 0)) == (lane < partner); \
      bool before = (v > ov) || (v == ov && vi < oi); \
      if(keepFirst != before){ v = ov; vi = oi; } \
    } \
  } }

// ======== fragment-major tiled split layout ========
// split[rowGroup][kTile][lane=64][8]  (u16). lane l -> row = rg*16 + (l&15), k = kt*32 + (l>>4)*8.

// ---------------- prep: weights transposes + splits + enc ----------------
__global__ void prep_k(const float* W5, const float* W2, const float* W3, const float* W4,
                       float* W5T, float* WT2, float* WT3, float* WT4,
                       u16* w5h, u16* w5m, u16* w5l, u16* wts,
                       unsigned* mx, unsigned* mn, int big){
  int i = blockIdx.x*256 + threadIdx.x;     // 262144
  if(!big){ int o = i>>9, c = i&511; W5T[c*512+o] = W5[i]; }   // fp32 W5T only for fallback
  { // tiled split of W5 (B-side rows = output cols o, k = input c). KT=16.
    int rg = i>>13, kt = (i>>9)&15, l = (i>>3)&63, j = i&7;
    int o = rg*16 + (l&15);
    int c = kt*32 + ((l>>4)<<3) + j;
    u16 h,m,lo; bf16split3(W5[(size_t)o*512 + c], h, m, lo);
    w5h[i]=h; w5m[i]=m; w5l[i]=lo; }
  if(i < 65536){ int c = i>>9, o = i&511;   // W4: [256][256] -> cat [128][512]
    WT4[i] = (o<256) ? W4[(size_t)o*256 + c] : W4[(size_t)(o-256)*256 + 128 + c]; }
  if(i < 16384){ int c = i>>8, o = i&255;   // W3: [128][128] -> cat [64][256]
    WT3[i] = (o<128) ? W3[(size_t)o*128 + c] : W3[(size_t)(o-128)*128 + 64 + c]; }
  if(i <  8192){ int c = i>>7, o = i&127;   // W2: [64][128] -> cat [64][128]
    WT2[i] = (o<64) ? W2[(size_t)o*128 + c] : W2[(size_t)(o-64)*128 + 64 + c]; }
  if(big){
    if(i < 65536){ // WT4 tiled split: rg over o (32), kt over c (4)
      int rg=i>>11, kt=(i>>9)&3, l=(i>>3)&63, j=i&7;
      int o = rg*16 + (l&15);
      int c = kt*32 + ((l>>4)<<3) + j;
      float v = (o<256) ? W4[(size_t)o*256 + c] : W4[(size_t)(o-256)*256 + 128 + c];
      u16 h,m,lo; bf16split3(v,h,m,lo);
      wts[WTS_4H+i]=h; wts[WTS_4M+i]=m; wts[WTS_4L+i]=lo; }
  }
  if(i <  4096){ mx[i] = 0x007FFFFFu; mn[i] = 0xFF800000u; }
}

// ---------------- KNN ----------------
template<int C>
__launch_bounds__(256) __global__ void sqnorm_k(const float* X, float* xx){
  int i = blockIdx.x*256 + threadIdx.x;   // BN
  const float* r = X + (size_t)i*C;
  float s = 0.f;
  #pragma unroll
  for(int c=0;c<C;c++) s = fmaf(r[c], r[c], s);
  xx[i] = s;
}

// 3-way bf16 split of X [BN][C] into fragment-major tiled layout.
template<int C>
__launch_bounds__(256) __global__ void split_k(const float* __restrict__ X,
    u16* __restrict__ xh, u16* __restrict__ xm, u16* __restrict__ xl){
  constexpr int KT = C/32;
  const size_t t = (size_t)blockIdx.x*256 + threadIdx.x;   // BN*C/8 chunks
  const int l = (int)(t & 63);
  const size_t tile = t >> 6;               // rgG*KT + kt
  const int kt = (int)(tile & (KT-1));
  const size_t rgG = tile / KT;             // global row group (BN/16 total)
  const size_t row = rgG*16 + (l & 15);
  const int k = kt*32 + ((l>>4)<<3);
  const float* p = X + row*C + k;
  float4 v0 = *(const float4*)p;
  float4 v1 = *(const float4*)(p+4);
  float vs[8] = {v0.x,v0.y,v0.z,v0.w,v1.x,v1.y,v1.z,v1.w};
  ushort8 H,M,L;
  #pragma unroll
  for(int j=0;j<8;j++){ u16 h,m,lo; bf16split3(vs[j],h,m,lo); H[j]=h; M[j]=m; L[j]=lo; }
  *(ushort8*)(xh + t*8) = H;
  *(ushort8*)(xm + t*8) = M;
  *(ushort8*)(xl + t*8) = L;
}

#define FMA_ROW(I) \
  acc[I][0]=fmaf(a,b0v,acc[I][0]); acc[I][1]=fmaf(a,b1v,acc[I][1]); \
  acc[I][2]=fmaf(a,b2v,acc[I][2]); acc[I][3]=fmaf(a,b3v,acc[I][3]); \
  acc[I][4]=fmaf(a,b4v,acc[I][4]); acc[I][5]=fmaf(a,b5v,acc[I][5]); \
  acc[I][6]=fmaf(a,b6v,acc[I][6]); acc[I][7]=fmaf(a,b7v,acc[I][7]);

// fallback fp32 dist GEMM
template<int C>
__launch_bounds__(256) __global__ void gemm_dist_k(const float* __restrict__ X, const float* __restrict__ xx,
                                                   float* __restrict__ dist, int b0){
  constexpr int AST = 188;
  __shared__ __align__(16) float a_sh[16*AST];
  __shared__ __align__(16) float b_sh[16*AST];
  __shared__ float sxn[128], sxm[128];
  const int tid = threadIdx.x;
  const int b   = b0 + blockIdx.z;
  const int mtile = blockIdx.x*128;
  const int ntile = blockIdx.y*128;
  const int tn = tid & 15, tm = tid >> 4;
  const float* Xb  = X  + (size_t)b*NN*C;
  const float* xxb = xx + (size_t)b*NN;
  if(tid < 128) sxn[tid] = xxb[ntile + tid];
  else          sxm[tid-128] = xxb[mtile + tid-128];
  float acc[8][8];
  #pragma unroll
  for(int i=0;i<8;i++){
    #pragma unroll
    for(int j=0;j<8;j++) acc[i][j]=0.f;
  }
  for(int cc=0; cc<C; cc+=16){
    __syncthreads();
    #pragma unroll
    for(int s=0;s<2;s++){
      int ii = tid + 256*s; int r = ii>>2, q = ii&3;
      int pr = r + 4*(r>>3);
      float4 va = *(const float4*)&Xb[(size_t)(ntile + r)*C + cc + 4*q];
      a_sh[(4*q+0)*AST + pr]=va.x; a_sh[(4*q+1)*AST + pr]=va.y;
      a_sh[(4*q+2)*AST + pr]=va.z; a_sh[(4*q+3)*AST + pr]=va.w;
      float4 vb = *(const float4*)&Xb[(size_t)(mtile + r)*C + cc + 4*q];
      b_sh[(4*q+0)*AST + pr]=vb.x; b_sh[(4*q+1)*AST + pr]=vb.y;
      b_sh[(4*q+2)*AST + pr]=vb.z; b_sh[(4*q+3)*AST + pr]=vb.w;
    }
    __syncthreads();
    #pragma unroll
    for(int c=0;c<16;c++){
      float4 A0 = *(const float4*)&a_sh[c*AST + 12*tn];
      float4 A1 = *(const float4*)&a_sh[c*AST + 12*tn + 4];
      float4 B0 = *(const float4*)&b_sh[c*AST + 12*tm];
      float4 B1 = *(const float4*)&b_sh[c*AST + 12*tm + 4];
      float b0v=B0.x,b1v=B0.y,b2v=B0.z,b3v=B0.w,b4v=B1.x,b5v=B1.y,b6v=B1.z,b7v=B1.w;
      float a;
      a=A0.x; FMA_ROW(0)
      a=A0.y; FMA_ROW(1)
      a=A0.z; FMA_ROW(2)
      a=A0.w; FMA_ROW(3)
      a=A1.x; FMA_ROW(4)
      a=A1.y; FMA_ROW(5)
      a=A1.z; FMA_ROW(6)
      a=A1.w; FMA_ROW(7)
    }
  }
  float xnr[8], xmr[8];
  #pragma unroll
  for(int i=0;i<8;i++){ xnr[i]=sxn[tn*8+i]; xmr[i]=sxm[tm*8+i]; }
  const size_t rowb = (size_t)blockIdx.z*NN + ntile + tn*8;
  #pragma unroll
  for(int i=0;i<8;i++){
    float4 w0, w1;
    w0.x=(2.f*acc[i][0]-xnr[i])-xmr[0]; w0.y=(2.f*acc[i][1]-xnr[i])-xmr[1];
    w0.z=(2.f*acc[i][2]-xnr[i])-xmr[2]; w0.w=(2.f*acc[i][3]-xnr[i])-xmr[3];
    w1.x=(2.f*acc[i][4]-xnr[i])-xmr[4]; w1.y=(2.f*acc[i][5]-xnr[i])-xmr[5];
    w1.z=(2.f*acc[i][6]-xnr[i])-xmr[6]; w1.w=(2.f*acc[i][7]-xnr[i])-xmr[7];
    float* dp = dist + (rowb + i)*NN + mtile + tm*8;
    *(float4*)dp = w0;
    *(float4*)(dp+4) = w1;
  }
}

// big path: exact-fp32-quality dist via split-bf16 MFMA (6 products of 3-way split).
// Chunked over batches (b0): dist holds blockDim.z batches, L3-resident between dist and sel.
template<int C>
__launch_bounds__(256) __global__ void mfma_dist_k(const u16* __restrict__ xh, const u16* __restrict__ xm,
    const u16* __restrict__ xl, const float* __restrict__ xx, float* __restrict__ dist, int b0){
  constexpr int KT = C/32;
  const int tid = threadIdx.x;
  const int l  = tid & 63, wv = tid >> 6;
  const int lg = l >> 4, lr = l & 15;
  const int cz = blockIdx.z;
  const int b  = b0 + cz;
  const int qrow0 = blockIdx.y*128 + (wv>>1)*64;   // query rows (A side, dist row)
  const int crow0 = blockIdx.x*128 + (wv&1)*64;    // candidate rows (B side, dist col)
  const size_t brg = (size_t)b*(NN/16);
  f32x4 acc[4][4];
  #pragma unroll
  for(int m=0;m<4;m++){
    #pragma unroll
    for(int n=0;n<4;n++) acc[m][n] = (f32x4){0.f,0.f,0.f,0.f};
  }
  const size_t abase = (brg + (qrow0>>4))*KT*512 + (size_t)l*8;
  const size_t bbase = (brg + (crow0>>4))*KT*512 + (size_t)l*8;
  for(int kt=0; kt<KT; kt++){
    short8 Ah[4], Am[4], Al[4], Bh[4], Bm[4], Bl[4];
    #pragma unroll
    for(int m=0;m<4;m++){
      size_t o = abase + (size_t)(m*KT + kt)*512;
      Ah[m] = *(const short8*)(xh + o);
      Am[m] = *(const short8*)(xm + o);
      Al[m] = *(const short8*)(xl + o);
    }
    #pragma unroll
    for(int n=0;n<4;n++){
      size_t o = bbase + (size_t)(n*KT + kt)*512;
      Bh[n] = *(const short8*)(xh + o);
      Bm[n] = *(const short8*)(xm + o);
      Bl[n] = *(const short8*)(xl + o);
    }
    #pragma unroll
    for(int m=0;m<4;m++){
      #pragma unroll
      for(int n=0;n<4;n++){
        acc[m][n] = __builtin_amdgcn_mfma_f32_16x16x32_bf16(Ah[m], Bh[n], acc[m][n], 0, 0, 0);
        acc[m][n] = __builtin_amdgcn_mfma_f32_16x16x32_bf16(Ah[m], Bm[n], acc[m][n], 0, 0, 0);
        acc[m][n] = __builtin_amdgcn_mfma_f32_16x16x32_bf16(Am[m], Bh[n], acc[m][n], 0, 0, 0);
        acc[m][n] = __builtin_amdgcn_mfma_f32_16x16x32_bf16(Ah[m], Bl[n], acc[m][n], 0, 0, 0);
        acc[m][n] = __builtin_amdgcn_mfma_f32_16x16x32_bf16(Al[m], Bh[n], acc[m][n], 0, 0, 0);
        acc[m][n] = __builtin_amdgcn_mfma_f32_16x16x32_bf16(Am[m], Bm[n], acc[m][n], 0, 0, 0);
      }
    }
  }
  const float* xxb = xx + (size_t)b*NN;
  float xxc[4];
  #pragma unroll
  for(int n=0;n<4;n++) xxc[n] = xxb[crow0 + n*16 + lr];
  #pragma unroll
  for(int m=0;m<4;m++){
    #pragma unroll
    for(int r=0;r<4;r++){
      int qr = qrow0 + m*16 + 4*lg + r;
      float xq = xxb[qr];
      float* dp = dist + ((size_t)cz*NN + qr)*NN + crow0;
      #pragma unroll
      for(int n=0;n<4;n++) dp[n*16 + lr] = (2.f*acc[m][n][r] - xq) - xxc[n];
    }
  }
}

// Wave-cooperative top-20: max-of-4 bitonic warm start + slim insertions, float4 scan.
__launch_bounds__(256) __global__ void sel_k(const float* __restrict__ dist, int* __restrict__ id,
                                             int b0, int nrows){
  const int w = (blockIdx.x*256 + threadIdx.x) >> 6;
  const int lane = threadIdx.x & 63;
  if(w >= nrows) return;
  const float* dr = dist + (size_t)w*NN;
  float4 c0 = *(const float4*)&dr[4*lane];
  float cd0[4] = {c0.x, c0.y, c0.z, c0.w};
  int jbest = 0; float v = cd0[0];
  #pragma unroll
  for(int j=1;j<4;j++){ if(cd0[j] > v){ v = cd0[j]; jbest = j; } }
  int vi = 4*lane + jbest;
  BITONIC64_DESC(v, vi)
  float lv = (lane < KK) ? v : -INFINITY;
  int   li = (lane < KK) ? vi : 0;
  float theta = readlane_f(lv, KK-1);
  #pragma unroll
  for(int j=0;j<4;j++){
    float cand = (j == jbest) ? -INFINITY : cd0[j];
    unsigned long long bal = __ballot(cand > theta);
    while(bal){
      int bpos = __ffsll((unsigned long long)bal) - 1;
      bal &= bal - 1;
      float cv = readlane_f(cand, bpos);
      if(cv > theta){
        int ci = 4*bpos + j;
        INSERT_CAND(cv, ci)
      }
    }
  }
  for(int ms=256; ms<NN; ms+=256){
    float4 c4 = *(const float4*)&dr[ms + 4*lane];
    #pragma unroll
    for(int j=0;j<4;j++){
      float cand = (j==0)?c4.x:(j==1)?c4.y:(j==2)?c4.z:c4.w;
      unsigned long long bal = __ballot(cand > theta);
      while(bal){
        int bpos = __ffsll((unsigned long long)bal) - 1;
        bal &= bal - 1;
        float cv = readlane_f(cand, bpos);
        if(cv > theta){
          int ci = ms + 4*bpos + j;
          INSERT_CAND(cv, ci)
        }
      }
    }
  }
  if(lane < KK) id[((size_t)b0*NN + w)*KK + lane] = li;
}

// L1 fused: inline C=3 distances + inline sqnorm, max-of-4 bitonic warm start.
__launch_bounds__(256) __global__ void sel3_k(const float* __restrict__ X, int* __restrict__ id){
  const int gw = (blockIdx.x*256 + threadIdx.x) >> 6;
  const int lane = threadIdx.x & 63;
  const int b = gw >> 11, n = gw & 2047;
  const float* Xb  = X + (size_t)b*NN*3;
  const float x0v = Xb[n*3], x1v = Xb[n*3+1], x2v = Xb[n*3+2];
  float xxn = 0.f;
  xxn = fmaf(x0v, x0v, xxn); xxn = fmaf(x1v, x1v, xxn); xxn = fmaf(x2v, x2v, xxn);
  float lv, theta; int li;
  {
    const float* p = Xb + (size_t)(4*lane)*3;
    float4 va = *(const float4*)p;
    float4 vb = *(const float4*)(p+4);
    float4 vc = *(const float4*)(p+8);
    float cx[4] = {va.x, va.w, vb.z, vc.y};
    float cy[4] = {va.y, vb.x, vb.w, vc.z};
    float cz[4] = {va.z, vb.y, vc.x, vc.w};
    float cd[4];
    #pragma unroll
    for(int j=0;j<4;j++){
      float s = 0.f;
      s = fmaf(x0v, cx[j], s); s = fmaf(x1v, cy[j], s); s = fmaf(x2v, cz[j], s);
      float xxm = 0.f;
      xxm = fmaf(cx[j], cx[j], xxm); xxm = fmaf(cy[j], cy[j], xxm); xxm = fmaf(cz[j], cz[j], xxm);
      cd[j] = (2.f*s - xxn) - xxm;
    }
    int jbest = 0; float v = cd[0];
    #pragma unroll
    for(int j=1;j<4;j++){ if(cd[j] > v){ v = cd[j]; jbest = j; } }
    int vi = 4*lane + jbest;
    BITONIC64_DESC(v, vi)
    lv = (lane < KK) ? v : -INFINITY;
    li = (lane < KK) ? vi : 0;
    theta = readlane_f(lv, KK-1);
    #pragma unroll
    for(int j=0;j<4;j++){
      float cand = (j == jbest) ? -INFINITY : cd[j];
      unsigned long long bal = __ballot(cand > theta);
      while(bal){
        int bpos = __ffsll((unsigned long long)bal) - 1;
        bal &= bal - 1;
        float cv = readlane_f(cand, bpos);
        if(cv > theta){
          int ci = 4*bpos + j;
          INSERT_CAND(cv, ci)
        }
      }
    }
  }
  for(int ms=256; ms<NN; ms+=256){
    const float* p = Xb + (size_t)(ms + 4*lane)*3;
    float4 va = *(const float4*)p;
    float4 vb = *(const float4*)(p+4);
    float4 vc = *(const float4*)(p+8);
    float cx[4] = {va.x, va.w, vb.z, vc.y};
    float cy[4] = {va.y, vb.x, vb.w, vc.z};
    float cz[4] = {va.z, vb.y, vc.x, vc.w};
    float cd[4];
    #pragma unroll
    for(int j=0;j<4;j++){
      float s = 0.f;
      s = fmaf(x0v, cx[j], s); s = fmaf(x1v, cy[j], s); s = fmaf(x2v, cz[j], s);
      float xxm = 0.f;
      xxm = fmaf(cx[j], cx[j], xxm); xxm = fmaf(cy[j], cy[j], xxm); xxm = fmaf(cz[j], cz[j], xxm);
      cd[j] = (2.f*s - xxn) - xxm;
    }
    #pragma unroll
    for(int j=0;j<4;j++){
      float cand = cd[j];
      unsigned long long bal = __ballot(cand > theta);
      while(bal){
        int bpos = __ffsll((unsigned long long)bal) - 1;
        bal &= bal - 1;
        float cv = readlane_f(cand, bpos);
        if(cv > theta){
          int ci = ms + 4*bpos + j;
          INSERT_CAND(cv, ci)
        }
      }
    }
  }
  if(lane < KK) id[(size_t)gw*KK + lane] = li;
}

// ---------------- qp ----------------
// L1: writes interleaved qp[row][128]: q at 0..63, p at 64..127
__launch_bounds__(256) __global__ void qp3_k(const float* X, const float* W, float* qp){
  const int t   = blockIdx.x*256 + threadIdx.x;
  const int row = t >> 3;
  const int c0  = (t & 7) * 8;
  float xn[3];
  #pragma unroll
  for(int c=0;c<3;c++) xn[c] = X[(size_t)row*3 + c];
  for(int oi=c0; oi<c0+8; oi++){
    const float* w = W + (size_t)oi*6;
    float aq=0.f, ap=0.f;
    #pragma unroll
    for(int c=0;c<3;c++){ aq = fmaf(xn[c], w[c], aq); ap = fmaf(xn[c], w[3+c], ap); }
    qp[(size_t)row*128 + oi]      = aq;
    qp[(size_t)row*128 + 64 + oi] = ap;
  }
}

// Tiled qp GEMM (big path, layers 2/3): C[BN x W2C] = X[BN x CIN] * WTcat[CIN x W2C].
template<int CIN, int W2C>
__launch_bounds__(256) __global__ void qp_gemm_k(const float* __restrict__ X, const float* __restrict__ WT,
                                                 float* __restrict__ qp){
  constexpr int ASTA = 92;    // 64 rows, pad 4 per 8: max pr = 63+28 = 91
  constexpr int ASTB = 188;
  __shared__ __align__(16) float a_sh[16*ASTA];
  __shared__ __align__(16) float b_sh[16*ASTB];
  const int tid = threadIdx.x;
  const int otile = blockIdx.x*128;
  const int rtile = blockIdx.y*64;
  const int tn = tid & 15, tm = tid >> 4;
  const int aoff = 4*tn + 4*(tn>>1);   // padded offset of row 4*tn
  float acc[4][8];
  #pragma unroll
  for(int i=0;i<4;i++){
    #pragma unroll
    for(int j=0;j<8;j++) acc[i][j]=0.f;
  }
  for(int cc=0; cc<CIN; cc+=16){
    __syncthreads();
    { int r = tid>>2, q = tid&3;          // 64 rows x 16 c = 256 float4, 1/thread
      int pr = r + 4*(r>>3);
      float4 va = *(const float4*)&X[(size_t)(rtile + r)*CIN + cc + 4*q];
      a_sh[(4*q+0)*ASTA + pr]=va.x; a_sh[(4*q+1)*ASTA + pr]=va.y;
      a_sh[(4*q+2)*ASTA + pr]=va.z; a_sh[(4*q+3)*ASTA + pr]=va.w; }
    #pragma unroll
    for(int s=0;s<2;s++){                 // 16 c x 128 cols = 512 float4, 2/thread
      int ii = tid + 256*s;
      int cl = ii>>5, o4 = ii&31;
      float4 vb = *(const float4*)&WT[(size_t)(cc+cl)*W2C + otile + 4*o4];
      *(float4*)&b_sh[cl*ASTB + 4*o4 + 4*(o4>>1)] = vb;
    }
    __syncthreads();
    #pragma unroll
    for(int c=0;c<16;c++){
      float4 A0 = *(const float4*)&a_sh[c*ASTA + aoff];
      float4 B0 = *(const float4*)&b_sh[c*ASTB + 12*tm];
      float4 B1 = *(const float4*)&b_sh[c*ASTB + 12*tm + 4];
      float b0v=B0.x,b1v=B0.y,b2v=B0.z,b3v=B0.w,b4v=B1.x,b5v=B1.y,b6v=B1.z,b7v=B1.w;
      float a;
      a=A0.x; FMA_ROW(0)
      a=A0.y; FMA_ROW(1)
      a=A0.z; FMA_ROW(2)
      a=A0.w; FMA_ROW(3)
    }
  }
  #pragma unroll
  for(int i=0;i<4;i++){
    float* dp = qp + (size_t)(rtile + tn*4 + i)*W2C + otile + tm*8;
    *(float4*)dp     = make_float4(acc[i][0],acc[i][1],acc[i][2],acc[i][3]);
    *(float4*)(dp+4) = make_float4(acc[i][4],acc[i][5],acc[i][6],acc[i][7]);
  }
}

// Layer-4 qp via split-bf16 MFMA, reusing x3 fragment-major splits (C=128) + tiled WT4 splits.
// qp[BN][512]; grid (512/128, BN/128); 4 waves 2x2, wave tile 64x64.
__launch_bounds__(256) __global__ void qp_mfma4_k(const u16* __restrict__ xh, const u16* __restrict__ xm,
    const u16* __restrict__ xl,
    const u16* __restrict__ wh, const u16* __restrict__ wm, const u16* __restrict__ wl,
    float* __restrict__ qp){
  constexpr int KT = 4;   // C=128
  const int tid = threadIdx.x;
  const int l  = tid & 63, wv = tid >> 6;
  const int lg = l >> 4, lr = l & 15;
  const int row0 = blockIdx.y*128 + (wv>>1)*64;
  const int col0 = blockIdx.x*128 + (wv&1)*64;
  f32x4 acc[4][4];
  #pragma unroll
  for(int m=0;m<4;m++){
    #pragma unroll
    for(int n=0;n<4;n++) acc[m][n] = (f32x4){0.f,0.f,0.f,0.f};
  }
  const size_t abase = (size_t)(row0>>4)*KT*512 + (size_t)l*8;
  const size_t bbase = (size_t)(col0>>4)*KT*512 + (size_t)l*8;
  for(int kt=0; kt<KT; kt++){
    short8 Ah[4], Am[4], Al[4], Bh[4], Bm[4], Bl[4];
    #pragma unroll
    for(int m=0;m<4;m++){
      size_t o = abase + (size_t)(m*KT + kt)*512;
      Ah[m] = *(const short8*)(xh + o);
      Am[m] = *(const short8*)(xm + o);
      Al[m] = *(const short8*)(xl + o);
    }
    #pragma unroll
    for(int n=0;n<4;n++){
      size_t o = bbase + (size_t)(n*KT + kt)*512;
      Bh[n] = *(const short8*)(wh + o);
      Bm[n] = *(const short8*)(wm + o);
      Bl[n] = *(const short8*)(wl + o);
    }
    #pragma unroll
    for(int m=0;m<4;m++){
      #pragma unroll
      for(int n=0;n<4;n++){
        acc[m][n] = __builtin_amdgcn_mfma_f32_16x16x32_bf16(Ah[m], Bh[n], acc[m][n], 0, 0, 0);
        acc[m][n] = __builtin_amdgcn_mfma_f32_16x16x32_bf16(Ah[m], Bm[n], acc[m][n], 0, 0, 0);
        acc[m][n] = __builtin_amdgcn_mfma_f32_16x16x32_bf16(Am[m], Bh[n], acc[m][n], 0, 0, 0);
        acc[m][n] = __builtin_amdgcn_mfma_f32_16x16x32_bf16(Ah[m], Bl[n], acc[m][n], 0, 0, 0);
        acc[m][n] = __builtin_amdgcn_mfma_f32_16x16x32_bf16(Al[m], Bh[n], acc[m][n], 0, 0, 0);
        acc[m][n] = __builtin_amdgcn_mfma_f32_16x16x32_bf16(Am[m], Bm[n], acc[m][n], 0, 0, 0);
      }
    }
  }
  #pragma unroll
  for(int m=0;m<4;m++){
    #pragma unroll
    for(int r=0;r<4;r++){
      int row = row0 + m*16 + 4*lg + r;
      float* dp = qp + (size_t)row*512 + col0;
      #pragma unroll
      for(int n=0;n<4;n++) dp[n*16 + lr] = acc[m][n][r];
    }
  }
}

// Gather from interleaved qp[row][2*COUT] (q | p); base = p - q computed here (bit-exact).
template<int COUT>
__launch_bounds__(256) __global__ void gather_qp_k(const float* __restrict__ qp, const int* __restrict__ idx,
    const float* g, const float* bb, float* out){
  const int t  = blockIdx.x*256 + threadIdx.x;   // BN*COUT
  const int o  = t % COUT;
  const int bn = t / COUT;
  const int b  = bn >> 11;
  const int* id = idx + (size_t)bn*KK;
  float qv = qp[(size_t)bn*(2*COUT) + o];
  float pv = qp[(size_t)bn*(2*COUT) + COUT + o];
  float base = pv - qv;
  float mx = -INFINITY, mn = INFINITY;
  #pragma unroll
  for(int k=0;k<KK;k++){
    int ik = id[k];
    float v = qp[((size_t)((b<<11) + ik))*(2*COUT) + o];
    mx = fmaxf(mx, v); mn = fminf(mn, v);
  }
  float a  = g[o] * RSQ;
  float bo = bb[o];
  out[(size_t)bn*COUT + o] = lrelu((a >= 0.f ? a*(mx+base) : a*(mn+base)) + bo);
}

// ---- fallback chunked qp (cat weight layout) + chunked gather ----
template<int CIN, int COUT>
__launch_bounds__(256) __global__ void qp64T_k(const float* __restrict__ X, const float* __restrict__ WT,
                                               int cb, float* __restrict__ q, float* __restrict__ bs){
  const int t   = blockIdx.x*256 + threadIdx.x;
  const int row = t >> 3;
  const int o0  = cb + (t & 7) * 8;
  float xn[CIN];
  #pragma unroll
  for(int c=0;c<CIN;c+=4){ float4 v = *(const float4*)(X + (size_t)row*CIN + c);
    xn[c]=v.x; xn[c+1]=v.y; xn[c+2]=v.z; xn[c+3]=v.w; }
  float aq[8], ap[8];
  #pragma unroll
  for(int j=0;j<8;j++){ aq[j]=0.f; ap[j]=0.f; }
  #pragma unroll 4
  for(int c=0;c<CIN;c++){
    float xc = xn[c];
    float4 wa0 = *(const float4*)&WT[(size_t)c*(2*COUT) + o0];
    float4 wa1 = *(const float4*)&WT[(size_t)c*(2*COUT) + o0 + 4];
    float4 wb0 = *(const float4*)&WT[(size_t)c*(2*COUT) + COUT + o0];
    float4 wb1 = *(const float4*)&WT[(size_t)c*(2*COUT) + COUT + o0 + 4];
    aq[0]=fmaf(xc,wa0.x,aq[0]); aq[1]=fmaf(xc,wa0.y,aq[1]); aq[2]=fmaf(xc,wa0.z,aq[2]); aq[3]=fmaf(xc,wa0.w,aq[3]);
    aq[4]=fmaf(xc,wa1.x,aq[4]); aq[5]=fmaf(xc,wa1.y,aq[5]); aq[6]=fmaf(xc,wa1.z,aq[6]); aq[7]=fmaf(xc,wa1.w,aq[7]);
    ap[0]=fmaf(xc,wb0.x,ap[0]); ap[1]=fmaf(xc,wb0.y,ap[1]); ap[2]=fmaf(xc,wb0.z,ap[2]); ap[3]=fmaf(xc,wb0.w,ap[3]);
    ap[4]=fmaf(xc,wb1.x,ap[4]); ap[5]=fmaf(xc,wb1.y,ap[5]); ap[6]=fmaf(xc,wb1.z,ap[6]); ap[7]=fmaf(xc,wb1.w,ap[7]);
  }
  float* qpp = q  + (size_t)row*64 + (o0-cb);
  float* bpp = bs + (size_t)row*64 + (o0-cb);
  *(float4*)qpp     = make_float4(aq[0],aq[1],aq[2],aq[3]);
  *(float4*)(qpp+4) = make_float4(aq[4],aq[5],aq[6],aq[7]);
  *(float4*)bpp     = make_float4(ap[0]-aq[0],ap[1]-aq[1],ap[2]-aq[2],ap[3]-aq[3]);
  *(float4*)(bpp+4) = make_float4(ap[4]-aq[4],ap[5]-aq[5],ap[6]-aq[6],ap[7]-aq[7]);
}

template<int CFULL>
__launch_bounds__(256) __global__ void gather_chunk_k(const float* q, const float* bs, const int* idx,
    const float* g, const float* bb, int cb, float* out){
  const int t  = blockIdx.x*256 + threadIdx.x;
  const int o  = t & 63;
  const int bn = t >> 6;
  const int b  = bn >> 11;
  const int* id = idx + (size_t)bn*KK;
  float base = bs[t];
  float mx = -INFINITY, mn = INFINITY;
  #pragma unroll
  for(int k=0;k<KK;k++){
    int ik = id[k];
    float v = q[((size_t)((b<<11) + ik))*64 + o];
    mx = fmaxf(mx, v); mn = fminf(mn, v);
  }
  float a  = g[cb+o] * RSQ;
  float bo = bb[cb+o];
  out[(size_t)bn*CFULL + cb + o] = lrelu((a >= 0.f ? a*(mx+base) : a*(mn+base)) + bo);
}

// ---------------- head (fallback): fp32 GEMM-tiled cat x W5T with fused max/min ----------------
__launch_bounds__(256) __global__ void w5gemm_k(const float* __restrict__ x1, const float* __restrict__ x2,
    const float* __restrict__ x3, const float* __restrict__ x4,
    const float* __restrict__ W5T, unsigned* mxe, unsigned* mne){
  constexpr int ASTA = 92;
  constexpr int ASTB = 188;
  __shared__ __align__(16) float a_sh[16*ASTA];
  __shared__ __align__(16) float b_sh[16*ASTB];
  const int tid = threadIdx.x;
  const int otile = blockIdx.x*128;
  const int rtile = blockIdx.y*64;
  const int b     = blockIdx.z;
  const int tn = tid & 15, tm = tid >> 4;
  const int aoff = 4*tn + 4*(tn>>1);
  const size_t row0 = (size_t)b*NN + rtile;
  float acc[4][8];
  #pragma unroll
  for(int i=0;i<4;i++){
    #pragma unroll
    for(int j=0;j<8;j++) acc[i][j]=0.f;
  }
  for(int cc=0; cc<512; cc+=16){
    const float* src; int stride, coff;
    if(cc<64)      { src=x1; stride=64;  coff=cc; }
    else if(cc<128){ src=x2; stride=64;  coff=cc-64; }
    else if(cc<256){ src=x3; stride=128; coff=cc-128; }
    else           { src=x4; stride=256; coff=cc-256; }
    __syncthreads();
    { int r = tid>>2, q = tid&3;
      int pr = r + 4*(r>>3);
      float4 va = *(const float4*)&src[(row0 + r)*stride + coff + 4*q];
      a_sh[(4*q+0)*ASTA + pr]=va.x; a_sh[(4*q+1)*ASTA + pr]=va.y;
      a_sh[(4*q+2)*ASTA + pr]=va.z; a_sh[(4*q+3)*ASTA + pr]=va.w; }
    #pragma unroll
    for(int s=0;s<2;s++){
      int ii = tid + 256*s;
      int cl = ii>>5, o4 = ii&31;
      float4 vb = *(const float4*)&W5T[(size_t)(cc+cl)*512 + otile + 4*o4];
      *(float4*)&b_sh[cl*ASTB + 4*o4 + 4*(o4>>1)] = vb;
    }
    __syncthreads();
    #pragma unroll
    for(int c=0;c<16;c++){
      float4 A0 = *(const float4*)&a_sh[c*ASTA + aoff];
      float4 B0 = *(const float4*)&b_sh[c*ASTB + 12*tm];
      float4 B1 = *(const float4*)&b_sh[c*ASTB + 12*tm + 4];
      float b0v=B0.x,b1v=B0.y,b2v=B0.z,b3v=B0.w,b4v=B1.x,b5v=B1.y,b6v=B1.z,b7v=B1.w;
      float a;
      a=A0.x; FMA_ROW(0)
      a=A0.y; FMA_ROW(1)
      a=A0.z; FMA_ROW(2)
      a=A0.w; FMA_ROW(3)
    }
  }
  #pragma unroll
  for(int j=0;j<8;j++){
    float M=-INFINITY, m=INFINITY;
    #pragma unroll
    for(int i=0;i<4;i++){ M=fmaxf(M,acc[i][j]); m=fminf(m,acc[i][j]); }
    #pragma unroll
    for(int d=1; d<16; d<<=1){
      M = fmaxf(M, __shfl_xor(M, d));
      m = fminf(m, __shfl_xor(m, d));
    }
    if(tn == 0){
      int o = otile + tm*8 + j;
      atomicMax(&mxe[b*512+o], encf(M));
      atomicMin(&mne[b*512+o], encf(m));
    }
  }
}

// ---------------- head (big): split-bf16 MFMA ----------------
// xcat 3-split into fragment-major tiled layout (KT=16, row space = BN).
__launch_bounds__(256) __global__ void cvt_k(const float* __restrict__ x1, const float* __restrict__ x2,
    const float* __restrict__ x3, const float* __restrict__ x4,
    u16* __restrict__ xh, u16* __restrict__ xm, u16* __restrict__ xl){
  const size_t t = (size_t)blockIdx.x*256 + threadIdx.x;   // BN*512/8 chunks
  const int l = (int)(t & 63);
  const size_t tile = t >> 6;           // rgG*16 + kt
  const int kt = (int)(tile & 15);
  const size_t rgG = tile >> 4;
  const size_t row = rgG*16 + (l & 15);
  const int col = kt*32 + ((l>>4)<<3);
  const float* src; int stride, coff;
  if(col<64)      { src=x1; stride=64;  coff=col; }
  else if(col<128){ src=x2; stride=64;  coff=col-64; }
  else if(col<256){ src=x3; stride=128; coff=col-128; }
  else            { src=x4; stride=256; coff=col-256; }
  const float* p = src + row*stride + coff;
  float4 v0 = *(const float4*)p;
  float4 v1 = *(const float4*)(p+4);
  float vs[8] = {v0.x,v0.y,v0.z,v0.w,v1.x,v1.y,v1.z,v1.w};
  ushort8 H, M, L;
  #pragma unroll
  for(int j=0;j<8;j++){ u16 h,m,lo; bf16split3(vs[j],h,m,lo); H[j]=h; M[j]=m; L[j]=lo; }
  *(ushort8*)(xh + t*8) = H;
  *(ushort8*)(xm + t*8) = M;
  *(ushort8*)(xl + t*8) = L;
}

// C[16384x512] = xcat * W5^T via 6 bf16 MFMA products (fp32-exact to ~2^-27), fp32 accum.
__launch_bounds__(256) __global__ void w5mfma_k(const u16* __restrict__ xh, const u16* __restrict__ xm,
    const u16* __restrict__ xl,
    const u16* __restrict__ wh, const u16* __restrict__ wm, const u16* __restrict__ wl,
    unsigned* mxe, unsigned* mne){
  const int tid = threadIdx.x;
  const int l  = tid & 63, wv = tid >> 6;
  const int lg = l >> 4, lr = l & 15;
  const int row0 = blockIdx.y*128 + (wv>>1)*64;   // M base of this wave (global BN rows)
  const int col0 = blockIdx.x*128 + (wv&1)*64;    // N base of this wave
  const int b = blockIdx.y >> 4;                  // 16 M-blocks per batch
  f32x4 acc[4][4];
  #pragma unroll
  for(int m=0;m<4;m++){
    #pragma unroll
    for(int n=0;n<4;n++) acc[m][n] = (f32x4){0.f,0.f,0.f,0.f};
  }
  const size_t abase = (size_t)(row0>>4)*16*512 + (size_t)l*8;
  const size_t bbase = (size_t)(col0>>4)*16*512 + (size_t)l*8;
  for(int kt=0; kt<16; kt++){
    short8 Ah[4], Am[4], Al[4], Bh[4], Bm[4], Bl[4];
    #pragma unroll
    for(int m=0;m<4;m++){
      size_t o = abase + (size_t)(m*16 + kt)*512;
      Ah[m] = *(const short8*)(xh + o);
      Am[m] = *(const short8*)(xm + o);
      Al[m] = *(const short8*)(xl + o);
    }
    #pragma unroll
    for(int n=0;n<4;n++){
      size_t o = bbase + (size_t)(n*16 + kt)*512;
      Bh[n] = *(const short8*)(wh + o);
      Bm[n] = *(const short8*)(wm + o);
      Bl[n] = *(const short8*)(wl + o);
    }
    #pragma unroll
    for(int m=0;m<4;m++){
      #pragma unroll
      for(int n=0;n<4;n++){
        acc[m][n] = __builtin_amdgcn_mfma_f32_16x16x32_bf16(Ah[m], Bh[n], acc[m][n], 0, 0, 0);
        acc[m][n] = __builtin_amdgcn_mfma_f32_16x16x32_bf16(Ah[m], Bm[n], acc[m][n], 0, 0, 0);
        acc[m][n] = __builtin_amdgcn_mfma_f32_16x16x32_bf16(Am[m], Bh[n], acc[m][n], 0, 0, 0);
        acc[m][n] = __builtin_amdgcn_mfma_f32_16x16x32_bf16(Ah[m], Bl[n], acc[m][n], 0, 0, 0);
        acc[m][n] = __builtin_amdgcn_mfma_f32_16x16x32_bf16(Al[m], Bh[n], acc[m][n], 0, 0, 0);
        acc[m][n] = __builtin_amdgcn_mfma_f32_16x16x32_bf16(Am[m], Bm[n], acc[m][n], 0, 0, 0);
      }
    }
  }
  #pragma unroll
  for(int n=0;n<4;n++){
    float M = -INFINITY, mnv = INFINITY;
    #pragma unroll
    for(int m=0;m<4;m++){
      #pragma unroll
      for(int r=0;r<4;r++){ float v = acc[m][n][r]; M = fmaxf(M, v); mnv = fminf(mnv, v); }
    }
    M   = fmaxf(M,   __shfl_xor(M, 16));   M   = fmaxf(M,   __shfl_xor(M, 32));
    mnv = fminf(mnv, __shfl_xor(mnv, 16)); mnv = fminf(mnv, __shfl_xor(mnv, 32));
    if(lg == 0){
      int o = col0 + n*16 + lr;
      atomicMax(&mxe[b*512+o], encf(M));
      atomicMin(&mne[b*512+o], encf(mnv));
    }
  }
}

__launch_bounds__(256) __global__ void final_k(const unsigned* mxe, const unsigned* mne,
    const float* g5, const float* b5, const float* Wemb, float* out){
  const int b = blockIdx.x, t = threadIdx.x;
  __shared__ float h[512];
  for(int o=t; o<512; o+=256){
    float mx = decf(mxe[b*512+o]);
    float mn = decf(mne[b*512+o]);
    float a  = g5[o] * RSQ;
    float bo = b5[o];
    float hv = lrelu((a >= 0.f ? a*mx : a*mn) + bo);
    h[o] = hv;
    out[b*512+o] = hv;
  }
  __syncthreads();
  const float* wr = Wemb + (size_t)t*512;
  float s = 0.f;
  for(int o=0;o<512;o+=4){
    float4 w4 = *(const float4*)(wr+o);
    s = fmaf(h[o],w4.x, fmaf(h[o+1],w4.y, fmaf(h[o+2],w4.z, fmaf(h[o+3],w4.w, s))));
  }
  out[4096 + b*256 + t] = s;
}

// ---------------- launch ----------------
extern "C" void kernel_launch(void* const* d_in, const int* in_sizes, int n_in,
                              void* d_out, int out_size, void* d_ws, size_t ws_size,
                              hipStream_t stream) {
  if (ws_size < WS_END * sizeof(float)) return;
  const bool big = ws_size >= WS_BIG_END * sizeof(float);   // deterministic per call

  const float* x0   = (const float*)d_in[0];
  const float* W1   = (const float*)d_in[1];
  const float* g1   = (const float*)d_in[2];
  const float* b1   = (const float*)d_in[3];
  const float* W2   = (const float*)d_in[4];
  const float* g2   = (const float*)d_in[5];
  const float* b2   = (const float*)d_in[6];
  const float* W3   = (const float*)d_in[7];
  const float* g3   = (const float*)d_in[8];
  const float* b3   = (const float*)d_in[9];
  const float* W4   = (const float*)d_in[10];
  const float* g4   = (const float*)d_in[11];
  const float* b4   = (const float*)d_in[12];
  const float* W5   = (const float*)d_in[13];
  const float* g5   = (const float*)d_in[14];
  const float* b5   = (const float*)d_in[15];
  const float* Wemb = (const float*)d_in[16];

  float* ws = (float*)d_ws;
  float* xx = ws + OFF_XX;
  float* x1 = ws + OFF_X1;  float* x2 = ws + OFF_X2;
  float* x3 = ws + OFF_X3;  float* x4 = ws + OFF_X4;
  float* qpS = ws + OFF_SC;               // L1 qp (width 128) + fallback chunked q/bs
  float* bsS = ws + OFF_SC + (size_t)BN*64;
  int*   id = (int*)(ws + OFF_ID);
  float* W5Tf = ws + OFF_W5T;
  unsigned* mxe = (unsigned*)(ws + OFF_MX);
  unsigned* mne = (unsigned*)(ws + OFF_MN);
  float* WT2 = ws + OFF_WT2;
  float* WT3 = ws + OFF_WT3;
  float* WT4 = ws + OFF_WT4;
  float* distD = ws + OFF_X3;   // fallback dual-batch
  float* distS = ws + OFF_X4;   // fallback single-batch
  float* distB = ws + OFF_BIG;  // big: 4-batch dist chunk, then reused as qp buffer / bf16 xcat
  u16* w5h = (u16*)(ws + OFF_SC + (size_t)BN*128);   // SC tail (free in both paths): 3x256KB
  u16* w5m = w5h + 512*512;
  u16* w5l = w5m + 512*512;
  u16* wts = (u16*)W5Tf;         // big path: tiled WT splits live in the (unused) W5T region
  float* out = (float*)d_out;

  prep_k<<<1024,256,0,stream>>>(W5, W2, W3, W4, W5Tf, WT2, WT3, WT4,
                                w5h, w5m, w5l, wts, mxe, mne, big ? 1 : 0);

  // layer 1 (3 -> 64)
  sel3_k<<<BN*64/256,256,0,stream>>>(x0, id);
  qp3_k<<<BN*8/256,256,0,stream>>>(x0, W1, qpS);
  gather_qp_k<64><<<BN*64/256,256,0,stream>>>(qpS, id, g1, b1, x1);

  if(big){
    float* qpB = distB;                      // reuse dist region post-sel
    // split scratch lives in x4 region (dead until layer-4 gather)
    u16* sh = (u16*)x4;
    // layer 2 (CIN=64 -> COUT=64, qp width 128)
    { u16* sm = sh + (size_t)BN*64; u16* sl = sm + (size_t)BN*64;
      sqnorm_k<64><<<BN/256,256,0,stream>>>(x1, xx);
      split_k<64><<<BN*64/8/256,256,0,stream>>>(x1, sh, sm, sl);
      for(int c0=0;c0<BB;c0+=4){
        mfma_dist_k<64><<<dim3(16,16,4),256,0,stream>>>(sh, sm, sl, xx, distB, c0);
        sel_k<<<(4*NN)/4,256,0,stream>>>(distB, id, c0, 4*NN);
      }
      qp_gemm_k<64,128><<<dim3(1,BN/64),256,0,stream>>>(x1, WT2, qpB);
      gather_qp_k<64><<<BN*64/256,256,0,stream>>>(qpB, id, g2, b2, x2); }
    // layer 3 (64 -> 128, qp width 256)
    { u16* sm = sh + (size_t)BN*64; u16* sl = sm + (size_t)BN*64;
      sqnorm_k<64><<<BN/256,256,0,stream>>>(x2, xx);
      split_k<64><<<BN*64/8/256,256,0,stream>>>(x2, sh, sm, sl);
      for(int c0=0;c0<BB;c0+=4){
        mfma_dist_k<64><<<dim3(16,16,4),256,0,stream>>>(sh, sm, sl, xx, distB, c0);
        sel_k<<<(4*NN)/4,256,0,stream>>>(distB, id, c0, 4*NN);
      }
      qp_gemm_k<64,256><<<dim3(2,BN/64),256,0,stream>>>(x2, WT3, qpB);
      gather_qp_k<128><<<BN*128/256,256,0,stream>>>(qpB, id, g3, b3, x3); }
    // layer 4 (128 -> 256, qp width 512)
    { u16* sm = sh + (size_t)BN*128; u16* sl = sm + (size_t)BN*128;
      sqnorm_k<128><<<BN/256,256,0,stream>>>(x3, xx);
      split_k<128><<<BN*128/8/256,256,0,stream>>>(x3, sh, sm, sl);
      for(int c0=0;c0<BB;c0+=4){
        mfma_dist_k<128><<<dim3(16,16,4),256,0,stream>>>(sh, sm, sl, xx, distB, c0);
        sel_k<<<(4*NN)/4,256,0,stream>>>(distB, id, c0, 4*NN);
      }
      // layer-4 qp on matrix cores, reusing x3 splits + tiled WT4 splits
      qp_mfma4_k<<<dim3(4,BN/128),256,0,stream>>>(sh, sm, sl,
          wts+WTS_4H, wts+WTS_4M, wts+WTS_4L, qpB);
      gather_qp_k<256><<<BN*256/256,256,0,stream>>>(qpB, id, g4, b4, x4); }
    // head: bf16 3-split (tiled) + 6-product MFMA
    u16* xh = (u16*)(ws + OFF_XCAT);
    u16* xm = xh + (size_t)BN*512;
    u16* xl = xm + (size_t)BN*512;
    cvt_k<<<BN*512/8/256,256,0,stream>>>(x1, x2, x3, x4, xh, xm, xl);
    w5mfma_k<<<dim3(4,128),256,0,stream>>>(xh, xm, xl, w5h, w5m, w5l, mxe, mne);
  } else {
    // fallback: chunked (R12 structure, cat weight layout)
    sqnorm_k<64><<<BN/256,256,0,stream>>>(x1, xx);
    for(int r=0;r<4;r++){
      gemm_dist_k<64><<<dim3(16,16,2),256,0,stream>>>(x1, xx, distD, 2*r);
      sel_k<<<(2*NN)/4,256,0,stream>>>(distD, id, 2*r, 2*NN);
    }
    qp64T_k<64,64><<<BN*8/256,256,0,stream>>>(x1, WT2, 0, qpS, bsS);
    gather_chunk_k<64><<<BN*64/256,256,0,stream>>>(qpS, bsS, id, g2, b2, 0, x2);

    sqnorm_k<64><<<BN/256,256,0,stream>>>(x2, xx);
    for(int r=0;r<4;r++){
      gemm_dist_k<64><<<dim3(16,16,2),256,0,stream>>>(x2, xx, distD, 2*r);
      sel_k<<<(2*NN)/4,256,0,stream>>>(distD, id, 2*r, 2*NN);
    }
    for(int cb=0; cb<128; cb+=64){
      qp64T_k<64,128><<<BN*8/256,256,0,stream>>>(x2, WT3, cb, qpS, bsS);
      gather_chunk_k<128><<<BN*64/256,256,0,stream>>>(qpS, bsS, id, g3, b3, cb, x3);
    }

    sqnorm_k<128><<<BN/256,256,0,stream>>>(x3, xx);
    for(int r=0;r<8;r++){
      gemm_dist_k<128><<<dim3(16,16,1),256,0,stream>>>(x3, xx, distS, r);
      sel_k<<<NN/4,256,0,stream>>>(distS, id, r, NN);
    }
    for(int cb=0; cb<256; cb+=64){
      qp64T_k<128,256><<<BN*8/256,256,0,stream>>>(x3, WT4, cb, qpS, bsS);
      gather_chunk_k<256><<<BN*64/256,256,0,stream>>>(qpS, bsS, id, g4, b4, cb, x4);
    }
    w5gemm_k<<<dim3(4,32,8),256,0,stream>>>(x1, x2, x3, x4, W5Tf, mxe, mne);
  }

  final_k<<<BB,256,0,stream>>>(mxe, mne, g5, b5, Wemb, out);
}